// Round 1
// baseline (4426.820 us; speedup 1.0000x reference)
//
#include <hip/hip_runtime.h>

// ---------------------------------------------------------------------------
// VQ-VAE forward, fp32 baseline.
// Layers: conv1(3->128,k4s2p1,relu) conv2(128->256,k4s2p1,relu)
//         conv3(256->64,k3s1p1)  VQ(512x64)  dec1(64->256,k3s1p1,relu)
//         deconv2(256->128,k4s2,relu)  deconv3(128->3,k4s2)
// Workspace layout (floats):
//   A   @ 0         : 33554432  (h1 [16,128,128,128], later deconv2 out)
//   B   @ 33554432  : 16777216  (h2 [16,256,64,64],  later dec1 out)
//   Z   @ 50331648  : 4194304   (z  [16,64,64,64])
//   Q   @ 54525952  : 4194304   (vq_x)
//   W2T @ 58720256  : 524288    transposed weights (built each call)
//   W3T @ 59244544  : 147456
//   W5T @ 59392000  : 147456
//   W6T @ 59539456  : 524288
//   W7T @ 60063744  : 6144
// ---------------------------------------------------------------------------

__device__ __forceinline__ float frelu(float v){ return v > 0.f ? v : 0.f; }

__global__ void k_zero1(float* p){ *p = 0.f; }

// wt[(ic*KHW + khw)*OC + oc] = w[((oc*IC)+ic)*KHW + khw]
__global__ __launch_bounds__(256) void k_wtrans(const float* __restrict__ w,
                                                float* __restrict__ wt,
                                                int OC, int IC, int KHW){
  int i = blockIdx.x * 256 + threadIdx.x;
  if (i >= OC * IC * KHW) return;
  int khw = i % KHW;
  int t = i / KHW;
  int ic = t % IC;
  int oc = t / IC;
  wt[(ic * KHW + khw) * OC + oc] = w[i];
}

// ---- conv1: x[16,3,256,256] -> y[16,128,128,128], k4 s2 p1, relu ----------
__global__ __launch_bounds__(256) void k_conv1(const float* __restrict__ x,
                                               const float* __restrict__ w,
                                               const float* __restrict__ bias,
                                               float* __restrict__ y){
  int i  = blockIdx.x * 256 + threadIdx.x;
  int ow = i & 127, oh = (i >> 7) & 127, oc = (i >> 14) & 127, b = i >> 21;
  const float* xb = x + b * 196608;
  const float* wp = w + oc * 48;
  float acc = bias[oc];
  #pragma unroll
  for (int c = 0; c < 3; c++){
    #pragma unroll
    for (int kh = 0; kh < 4; kh++){
      int ih = oh * 2 - 1 + kh;
      if ((unsigned)ih >= 256u) continue;
      #pragma unroll
      for (int kw = 0; kw < 4; kw++){
        int iw = ow * 2 - 1 + kw;
        if ((unsigned)iw >= 256u) continue;
        acc = fmaf(xb[c * 65536 + ih * 256 + iw], wp[c * 16 + kh * 4 + kw], acc);
      }
    }
  }
  y[i] = frelu(acc);
}

// ---- conv2: [16,128,128,128] -> [16,256,64,64], k4 s2 p1, relu ------------
// block: 8x8 out tile, all 256 oc. thread = (tq 0..63 -> 4 oc, sq 0..3 -> 16 sp)
__global__ __launch_bounds__(256) void k_conv2(const float* __restrict__ xin,
                                               const float* __restrict__ wt,
                                               const float* __restrict__ bias,
                                               float* __restrict__ y){
  __shared__ float lds[8 * 324];   // [8 ic][18][18]
  int t = threadIdx.x;
  int tq = t & 63, sq = t >> 6;
  int bid = blockIdx.x;
  int b = bid >> 6, tile = bid & 63;
  int oh0 = (tile >> 3) * 8, ow0 = (tile & 7) * 8;
  int ih0 = oh0 * 2 - 1, iw0 = ow0 * 2 - 1;
  float acc[4][16];
  #pragma unroll
  for (int j = 0; j < 4; j++)
    #pragma unroll
    for (int s = 0; s < 16; s++) acc[j][s] = 0.f;

  for (int ic0 = 0; ic0 < 128; ic0 += 8){
    __syncthreads();
    for (int e = t; e < 8 * 324; e += 256){
      int ic = e / 324, rem = e - ic * 324;
      int r = rem / 18, c = rem - r * 18;
      int ih = ih0 + r, iw = iw0 + c;
      float v = 0.f;
      if ((unsigned)ih < 128u && (unsigned)iw < 128u)
        v = xin[((b * 128 + ic0 + ic) << 14) + (ih << 7) + iw];
      lds[e] = v;
    }
    __syncthreads();
    #pragma unroll 1
    for (int ic = 0; ic < 8; ic++){
      const float* lp = lds + ic * 324;
      #pragma unroll 1
      for (int khw = 0; khw < 16; khw++){
        int kh = khw >> 2, kw = khw & 3;
        float4 wv = *(const float4*)(wt + ((ic0 + ic) * 16 + khw) * 256 + tq * 4);
        const float* lrow = lp + kh * 18 + kw;
        #pragma unroll
        for (int s = 0; s < 16; s++){
          int sg = sq * 16 + s;
          float xv = lrow[(sg >> 3) * 36 + (sg & 7) * 2];
          acc[0][s] = fmaf(wv.x, xv, acc[0][s]);
          acc[1][s] = fmaf(wv.y, xv, acc[1][s]);
          acc[2][s] = fmaf(wv.z, xv, acc[2][s]);
          acc[3][s] = fmaf(wv.w, xv, acc[3][s]);
        }
      }
    }
  }
  #pragma unroll
  for (int j = 0; j < 4; j++){
    int oc = tq * 4 + j;
    float bv = bias[oc];
    #pragma unroll
    for (int s = 0; s < 16; s++){
      int sg = sq * 16 + s;
      y[((b * 256 + oc) << 12) + ((oh0 + (sg >> 3)) << 6) + (ow0 + (sg & 7))] =
          frelu(acc[j][s] + bv);
    }
  }
}

// ---- conv3: [16,256,64,64] -> z[16,64,64,64], k3 s1 p1, no relu -----------
// block: 8x16 out tile, 64 oc. thread = (tq 0..15 -> 4 oc, sq 0..15 -> 8 sp)
__global__ __launch_bounds__(256) void k_conv3(const float* __restrict__ xin,
                                               const float* __restrict__ wt,
                                               const float* __restrict__ bias,
                                               float* __restrict__ z){
  __shared__ float lds[8 * 180];   // [8 ic][10][18]
  int t = threadIdx.x;
  int tq = t & 15, sq = t >> 4;
  int bid = blockIdx.x;
  int b = bid >> 5, tile = bid & 31;
  int oh0 = (tile >> 2) * 8, ow0 = (tile & 3) * 16;
  float acc[4][8];
  #pragma unroll
  for (int j = 0; j < 4; j++)
    #pragma unroll
    for (int s = 0; s < 8; s++) acc[j][s] = 0.f;

  for (int ic0 = 0; ic0 < 256; ic0 += 8){
    __syncthreads();
    for (int e = t; e < 8 * 180; e += 256){
      int ic = e / 180, rem = e - ic * 180;
      int r = rem / 18, c = rem - r * 18;
      int ih = oh0 - 1 + r, iw = ow0 - 1 + c;
      float v = 0.f;
      if ((unsigned)ih < 64u && (unsigned)iw < 64u)
        v = xin[((b * 256 + ic0 + ic) << 12) + (ih << 6) + iw];
      lds[e] = v;
    }
    __syncthreads();
    #pragma unroll 1
    for (int ic = 0; ic < 8; ic++){
      const float* lp = lds + ic * 180;
      #pragma unroll 1
      for (int khw = 0; khw < 9; khw++){
        int kh = khw / 3, kw = khw - kh * 3;
        float4 wv = *(const float4*)(wt + ((ic0 + ic) * 9 + khw) * 64 + tq * 4);
        const float* lrow = lp + kh * 18 + kw;
        #pragma unroll
        for (int s = 0; s < 8; s++){
          int sg = sq * 8 + s;
          float xv = lrow[(sg >> 4) * 18 + (sg & 15)];
          acc[0][s] = fmaf(wv.x, xv, acc[0][s]);
          acc[1][s] = fmaf(wv.y, xv, acc[1][s]);
          acc[2][s] = fmaf(wv.z, xv, acc[2][s]);
          acc[3][s] = fmaf(wv.w, xv, acc[3][s]);
        }
      }
    }
  }
  #pragma unroll
  for (int j = 0; j < 4; j++){
    int oc = tq * 4 + j;
    float bv = bias[oc];
    #pragma unroll
    for (int s = 0; s < 8; s++){
      int sg = sq * 8 + s;
      z[((b * 64 + oc) << 12) + ((oh0 + (sg >> 4)) << 6) + (ow0 + (sg & 15))] =
          acc[j][s] + bv;
    }
  }
}

// ---- VQ: z[16,64,64,64] -> vqx (gathered codes), loss ---------------------
__global__ __launch_bounds__(256) void k_vq(const float* __restrict__ z,
                                            const float* __restrict__ cb,
                                            float* __restrict__ vqx,
                                            float* __restrict__ lossp){
  __shared__ float cl[128 * 64];
  __shared__ float cn[128];
  __shared__ float wsum[4];
  int n = blockIdx.x * 256 + threadIdx.x;
  int b = n >> 12, hw = n & 4095;
  const float* zp = z + b * 262144 + hw;
  float zr[64];
  float znorm = 0.f;
  #pragma unroll
  for (int d = 0; d < 64; d++){ zr[d] = zp[d << 12]; znorm = fmaf(zr[d], zr[d], znorm); }
  float best = 3.4e38f; int bi = 0;
  for (int k0 = 0; k0 < 512; k0 += 128){
    __syncthreads();
    for (int e = threadIdx.x; e < 8192; e += 256) cl[e] = cb[(k0 << 6) + e];
    __syncthreads();
    if (threadIdx.x < 128){
      const float* cp = cl + threadIdx.x * 64;
      float s = 0.f;
      #pragma unroll
      for (int d = 0; d < 64; d++) s = fmaf(cp[d], cp[d], s);
      cn[threadIdx.x] = s;
    }
    __syncthreads();
    #pragma unroll 1
    for (int k = 0; k < 128; k++){
      const float* cp = cl + (k << 6);
      float dot = 0.f;
      #pragma unroll
      for (int d = 0; d < 64; d++) dot = fmaf(zr[d], cp[d], dot);
      float d2 = znorm - 2.f * dot + cn[k];
      if (d2 < best){ best = d2; bi = k0 + k; }
    }
  }
  const float* q = cb + bi * 64;
  float* vp = vqx + b * 262144 + hw;
  float ls = 0.f;
  #pragma unroll
  for (int d = 0; d < 64; d++){
    float qd = q[d];
    float df = qd - zr[d];
    ls = fmaf(df, df, ls);
    vp[d << 12] = qd;
  }
  #pragma unroll
  for (int off = 32; off > 0; off >>= 1) ls += __shfl_down(ls, off);
  int lane = threadIdx.x & 63, wid = threadIdx.x >> 6;
  if (lane == 0) wsum[wid] = ls;
  __syncthreads();
  if (threadIdx.x == 0){
    float tot = (wsum[0] + wsum[1]) + (wsum[2] + wsum[3]);
    atomicAdd(lossp, tot * (1.25f / 4194304.f));
  }
}

// ---- dec1: [16,64,64,64] -> [16,256,64,64], k3 s1 p1, relu ----------------
// block: 8x16 tile, 128 oc (half). thread = (tq 0..31 -> 4 oc, sq 0..7 -> 16 sp)
__global__ __launch_bounds__(256) void k_dec1(const float* __restrict__ xin,
                                              const float* __restrict__ wt,
                                              const float* __restrict__ bias,
                                              float* __restrict__ y){
  __shared__ float lds[8 * 180];   // [8 ic][10][18]
  int t = threadIdx.x;
  int tq = t & 31, sq = t >> 5;
  int bid = blockIdx.x;
  int tile = bid & 31, half = (bid >> 5) & 1, b = bid >> 6;
  int oh0 = (tile >> 2) * 8, ow0 = (tile & 3) * 16;
  int ocb = half * 128;
  float acc[4][16];
  #pragma unroll
  for (int j = 0; j < 4; j++)
    #pragma unroll
    for (int s = 0; s < 16; s++) acc[j][s] = 0.f;

  for (int ic0 = 0; ic0 < 64; ic0 += 8){
    __syncthreads();
    for (int e = t; e < 8 * 180; e += 256){
      int ic = e / 180, rem = e - ic * 180;
      int r = rem / 18, c = rem - r * 18;
      int ih = oh0 - 1 + r, iw = ow0 - 1 + c;
      float v = 0.f;
      if ((unsigned)ih < 64u && (unsigned)iw < 64u)
        v = xin[((b * 64 + ic0 + ic) << 12) + (ih << 6) + iw];
      lds[e] = v;
    }
    __syncthreads();
    #pragma unroll 1
    for (int ic = 0; ic < 8; ic++){
      const float* lp = lds + ic * 180;
      #pragma unroll 1
      for (int khw = 0; khw < 9; khw++){
        int kh = khw / 3, kw = khw - kh * 3;
        float4 wv = *(const float4*)(wt + ((ic0 + ic) * 9 + khw) * 256 + ocb + tq * 4);
        const float* lrow = lp + (sq + kh) * 18 + kw;
        #pragma unroll
        for (int s = 0; s < 16; s++){
          float xv = lrow[s];
          acc[0][s] = fmaf(wv.x, xv, acc[0][s]);
          acc[1][s] = fmaf(wv.y, xv, acc[1][s]);
          acc[2][s] = fmaf(wv.z, xv, acc[2][s]);
          acc[3][s] = fmaf(wv.w, xv, acc[3][s]);
        }
      }
    }
  }
  #pragma unroll
  for (int j = 0; j < 4; j++){
    int oc = ocb + tq * 4 + j;
    float bv = bias[oc];
    #pragma unroll
    for (int s = 0; s < 16; s++){
      y[((b * 256 + oc) << 12) + ((oh0 + sq) << 6) + (ow0 + s)] =
          frelu(acc[j][s] + bv);
    }
  }
}

// ---- deconv2: [16,256,64,64] -> [16,128,128,128], transposed k4 s2 p1, relu
// out tile 16x16 (input tile 8x8 +halo), 64 oc per block.
// thread = (tq 0..15 -> 4 oc, sq 0..15 -> parity(2x2) x 16 sp)
__global__ __launch_bounds__(256) void k_deconv2(const float* __restrict__ xin,
                                                 const float* __restrict__ wt,
                                                 const float* __restrict__ bias,
                                                 float* __restrict__ y){
  __shared__ float lds[8 * 100];   // [8 ic][10][10]
  int t = threadIdx.x;
  int tq = t & 15, sq = t >> 4;
  int po = (sq >> 1) & 1, pw = sq & 1, qr = sq >> 2;
  int bid = blockIdx.x;
  int tile = bid & 63, half = (bid >> 6) & 1, b = bid >> 7;
  int y0 = (tile >> 3) * 8, x0 = (tile & 7) * 8;
  int ocb = half * 64;
  float acc[4][16];
  #pragma unroll
  for (int j = 0; j < 4; j++)
    #pragma unroll
    for (int s = 0; s < 16; s++) acc[j][s] = 0.f;

  for (int ic0 = 0; ic0 < 256; ic0 += 8){
    __syncthreads();
    for (int e = t; e < 800; e += 256){
      int ic = e / 100, rem = e - ic * 100;
      int r = rem / 10, c = rem - r * 10;
      int ih = y0 - 1 + r, iw = x0 - 1 + c;
      float v = 0.f;
      if ((unsigned)ih < 64u && (unsigned)iw < 64u)
        v = xin[((b * 256 + ic0 + ic) << 12) + (ih << 6) + iw];
      lds[e] = v;
    }
    __syncthreads();
    #pragma unroll 1
    for (int ic = 0; ic < 8; ic++){
      const float* lp = lds + ic * 100;
      #pragma unroll
      for (int dh = 0; dh < 2; dh++){
        #pragma unroll
        for (int dw = 0; dw < 2; dw++){
          int kh = 2 * dh + po, kw = 2 * dw + pw;
          float4 wv = *(const float4*)(wt + ((ic0 + ic) * 16 + kh * 4 + kw) * 128 +
                                       ocb + tq * 4);
          #pragma unroll
          for (int s = 0; s < 16; s++){
            int yy = qr * 2 + (s >> 3), xx = s & 7;
            float xv = lp[(yy + dh + po) * 10 + (xx + dw + pw)];
            acc[0][s] = fmaf(wv.x, xv, acc[0][s]);
            acc[1][s] = fmaf(wv.y, xv, acc[1][s]);
            acc[2][s] = fmaf(wv.z, xv, acc[2][s]);
            acc[3][s] = fmaf(wv.w, xv, acc[3][s]);
          }
        }
      }
    }
  }
  #pragma unroll
  for (int j = 0; j < 4; j++){
    int oc = ocb + tq * 4 + j;
    float bv = bias[oc];
    #pragma unroll
    for (int s = 0; s < 16; s++){
      int yy = qr * 2 + (s >> 3), xx = s & 7;
      int oh = 2 * (y0 + yy) + po, ow = 2 * (x0 + xx) + pw;
      y[((b * 128 + oc) << 14) + (oh << 7) + ow] = frelu(acc[j][s] + bv);
    }
  }
}

// ---- deconv3: [16,128,128,128] -> out[16,3,256,256], transposed k4 s2 p1 --
// out tile 16x16, thread = 1 position x 3 oc.
__global__ __launch_bounds__(256) void k_deconv3(const float* __restrict__ xin,
                                                 const float* __restrict__ wt,
                                                 const float* __restrict__ bias,
                                                 float* __restrict__ out){
  __shared__ float lds[8 * 100];   // [8 ic][10][10]
  int t = threadIdx.x;
  int loh = t >> 4, low = t & 15;
  int po = loh & 1, pw = low & 1, yy = loh >> 1, xx = low >> 1;
  int bid = blockIdx.x;
  int tile = bid & 255, b = bid >> 8;
  int oh0 = (tile >> 4) * 16, ow0 = (tile & 15) * 16;
  int y0 = oh0 >> 1, x0 = ow0 >> 1;
  float a0 = bias[0], a1 = bias[1], a2 = bias[2];

  for (int ic0 = 0; ic0 < 128; ic0 += 8){
    __syncthreads();
    for (int e = t; e < 800; e += 256){
      int ic = e / 100, rem = e - ic * 100;
      int r = rem / 10, c = rem - r * 10;
      int ih = y0 - 1 + r, iw = x0 - 1 + c;
      float v = 0.f;
      if ((unsigned)ih < 128u && (unsigned)iw < 128u)
        v = xin[((b * 128 + ic0 + ic) << 14) + (ih << 7) + iw];
      lds[e] = v;
    }
    __syncthreads();
    #pragma unroll 1
    for (int ic = 0; ic < 8; ic++){
      const float* lp = lds + ic * 100;
      #pragma unroll
      for (int dh = 0; dh < 2; dh++){
        #pragma unroll
        for (int dw = 0; dw < 2; dw++){
          float xv = lp[(yy + dh + po) * 10 + (xx + dw + pw)];
          int khw = (2 * dh + po) * 4 + (2 * dw + pw);
          const float* wp = wt + ((ic0 + ic) * 16 + khw) * 3;
          a0 = fmaf(xv, wp[0], a0);
          a1 = fmaf(xv, wp[1], a1);
          a2 = fmaf(xv, wp[2], a2);
        }
      }
    }
  }
  int oh = oh0 + loh, ow = ow0 + low;
  out[(b * 3 + 0) * 65536 + oh * 256 + ow] = a0;
  out[(b * 3 + 1) * 65536 + oh * 256 + ow] = a1;
  out[(b * 3 + 2) * 65536 + oh * 256 + ow] = a2;
}

// ---------------------------------------------------------------------------
extern "C" void kernel_launch(void* const* d_in, const int* in_sizes, int n_in,
                              void* d_out, int out_size, void* d_ws, size_t ws_size,
                              hipStream_t stream){
  const float* x   = (const float*)d_in[0];
  const float* ew1 = (const float*)d_in[1];
  const float* eb1 = (const float*)d_in[2];
  const float* ew2 = (const float*)d_in[3];
  const float* eb2 = (const float*)d_in[4];
  const float* ew3 = (const float*)d_in[5];
  const float* eb3 = (const float*)d_in[6];
  const float* cb  = (const float*)d_in[7];
  const float* dw1 = (const float*)d_in[8];
  const float* db1 = (const float*)d_in[9];
  const float* dw2 = (const float*)d_in[10];
  const float* db2 = (const float*)d_in[11];
  const float* dw3 = (const float*)d_in[12];
  const float* db3 = (const float*)d_in[13];
  float* out = (float*)d_out;
  float* ws  = (float*)d_ws;

  float* A   = ws;
  float* Bf  = ws + 33554432;
  float* Z   = ws + 50331648;
  float* Q   = ws + 54525952;
  float* W2T = ws + 58720256;
  float* W3T = ws + 59244544;
  float* W5T = ws + 59392000;
  float* W6T = ws + 59539456;
  float* W7T = ws + 60063744;

  // weight transposes (cheap; inputs restored every call)
  k_wtrans<<<2048, 256, 0, stream>>>(ew2, W2T, 256, 128, 16);
  k_wtrans<<<576,  256, 0, stream>>>(ew3, W3T, 64, 256, 9);
  k_wtrans<<<576,  256, 0, stream>>>(dw1, W5T, 256, 64, 9);
  k_wtrans<<<2048, 256, 0, stream>>>(dw2, W6T, 128, 256, 16);
  k_wtrans<<<24,   256, 0, stream>>>(dw3, W7T, 3, 128, 16);

  k_zero1<<<1, 1, 0, stream>>>(out + 3145728);

  k_conv1<<<131072, 256, 0, stream>>>(x, ew1, eb1, A);
  k_conv2<<<1024,   256, 0, stream>>>(A, W2T, eb2, Bf);
  k_conv3<<<512,    256, 0, stream>>>(Bf, W3T, eb3, Z);
  k_vq<<<256,       256, 0, stream>>>(Z, cb, Q, out + 3145728);
  k_dec1<<<1024,    256, 0, stream>>>(Q, W5T, db1, Bf);
  k_deconv2<<<2048, 256, 0, stream>>>(Bf, W6T, db2, A);
  k_deconv3<<<4096, 256, 0, stream>>>(A, W7T, db3, out);
}

// Round 3
// 1245.256 us; speedup vs baseline: 3.5549x; 3.5549x over previous
//
#include <hip/hip_runtime.h>

// ---------------------------------------------------------------------------
// VQ-VAE forward, MFMA version.
// Encoder conv2/conv3 + VQ distances: split-bf16 3-product MFMA (~fp32 acc).
// Decoder dec1/deconv2/deconv3: single bf16 MFMA.
// Activations NHWC. Weights pre-packed into per-lane MFMA fragment layout.
//
// MFMA 16x16x32 bf16 fragment convention (gfx950, learn_hip m89-verified):
//   A[m][k]: lane l, j in 0..7 -> A[l&15][(l>>4)*8 + j]
//   B[k][n]: lane l, j          -> B[(l>>4)*8 + j][l&15]
//   D[m][n]: lane l, r in 0..3  -> D[(l>>4)*4 + r][l&15]
//
// LDS input staging layout (all conv kernels): granules of 16B (8 bf16 ic):
//   granule(g, r, c) = g*R*C + r*C + c     (g = ic-octet 0..3 within 32-ic)
//
// Workspace (byte offsets):
//   H1  f32 NHWC [16][128][128][128]   @ 0          (134,217,728)
//   H2H bf16 NHWC [16][64][64][256]    @ 134217728  (33,554,432)
//   H2L bf16                           @ 167772160  (33,554,432)
//   QX  bf16 NHWC [16][64][64][64]     @ 134217728  (reuse after conv3)
//   D1  bf16 NHWC [16][64][64][256]    @ 0          (reuse after conv2)
//   D2  bf16 NHWC [16][128][128][128]  @ 150994944  (33,554,432)
//   ZF  f32 [65536][64]                @ 201326592  (16,777,216)
//   IDX int32 [65536]                  @ 218103808  (262,144)
//   weight frag buffers                @ 218365952  (~4.3 MB)
// ---------------------------------------------------------------------------

typedef __attribute__((ext_vector_type(8))) short bf16x8;
typedef __attribute__((ext_vector_type(4))) short s16x4;
typedef __attribute__((ext_vector_type(4))) float f32x4;

#define MFMA16(a,b,c) __builtin_amdgcn_mfma_f32_16x16x32_bf16(a,b,c,0,0,0)

__device__ __forceinline__ ushort f2bf(float f){
  uint u = __float_as_uint(f);
  return (ushort)((u + 0x7fffu + ((u >> 16) & 1u)) >> 16);
}
__device__ __forceinline__ float bf2f(ushort h){
  return __uint_as_float(((uint)h) << 16);
}
__device__ __forceinline__ float frelu(float v){ return v > 0.f ? v : 0.f; }

__global__ void k_zero1(float* p){ *p = 0.f; }

// ---------------- weight prep kernels --------------------------------------
// W2F[khw16][icb4][ocT16][lane64][j8], hi+lo
__global__ __launch_bounds__(256) void k_w2f(const float* __restrict__ w,
                                             ushort* __restrict__ fh, ushort* __restrict__ fl){
  int i = blockIdx.x*256 + threadIdx.x;            // 524288
  int j = i & 7, l = (i >> 3) & 63, rest = i >> 9;
  int ocT = rest & 15, icb = (rest >> 4) & 3, khw = rest >> 6;
  int oc = ocT*16 + (l & 15);
  int ic = icb*32 + (l >> 4)*8 + j;
  float v = w[(oc*128 + ic)*16 + khw];
  ushort h = f2bf(v);
  fh[i] = h; fl[i] = f2bf(v - bf2f(h));
}
// W3F[khw9][icb8][ocT4][...], hi+lo
__global__ __launch_bounds__(256) void k_w3f(const float* __restrict__ w,
                                             ushort* __restrict__ fh, ushort* __restrict__ fl){
  int i = blockIdx.x*256 + threadIdx.x;            // 147456
  if (i >= 147456) return;
  int j = i & 7, l = (i >> 3) & 63, rest = i >> 9;
  int ocT = rest & 3, r2 = rest >> 2;
  int icb = r2 & 7, khw = r2 >> 3;
  int oc = ocT*16 + (l & 15);
  int ic = icb*32 + (l >> 4)*8 + j;
  float v = w[(oc*256 + ic)*9 + khw];
  ushort h = f2bf(v);
  fh[i] = h; fl[i] = f2bf(v - bf2f(h));
}
// W5F[khw9][icb2][ocT16][...], single
__global__ __launch_bounds__(256) void k_w5f(const float* __restrict__ w,
                                             ushort* __restrict__ f){
  int i = blockIdx.x*256 + threadIdx.x;            // 147456
  if (i >= 147456) return;
  int j = i & 7, l = (i >> 3) & 63, rest = i >> 9;
  int ocT = rest & 15, r2 = rest >> 4;
  int icb = r2 & 1, khw = r2 >> 1;
  int oc = ocT*16 + (l & 15);
  int ic = icb*32 + (l >> 4)*8 + j;
  f[i] = f2bf(w[(oc*64 + ic)*9 + khw]);
}
// W6F[par4][dhw4][icb8][ocT8][...], single
__global__ __launch_bounds__(256) void k_w6f(const float* __restrict__ w,
                                             ushort* __restrict__ f){
  int i = blockIdx.x*256 + threadIdx.x;            // 524288
  int j = i & 7, l = (i >> 3) & 63, rest = i >> 9;
  int ocT = rest & 7, icb = (rest >> 3) & 7, dhw = (rest >> 6) & 3, par = rest >> 8;
  int po = par >> 1, pw = par & 1;
  int kh = po + 2*(dhw >> 1), kw = pw + 2*(dhw & 1);
  int oc = ocT*16 + (l & 15);
  int ic = icb*32 + (l >> 4)*8 + j;
  f[i] = f2bf(w[(oc*256 + ic)*16 + kh*4 + kw]);
}
// W7F[par4][icb4][dhw4][1 ocT pad16][...], single
__global__ __launch_bounds__(256) void k_w7f(const float* __restrict__ w,
                                             ushort* __restrict__ f){
  int i = blockIdx.x*256 + threadIdx.x;            // 32768
  if (i >= 32768) return;
  int j = i & 7, l = (i >> 3) & 63, rest = i >> 9;
  int dhw = rest & 3, icb = (rest >> 2) & 3, par = (rest >> 4) & 3;
  int po = par >> 1, pw = par & 1;
  int kh = po + 2*(dhw >> 1), kw = pw + 2*(dhw & 1);
  int ocr = l & 15;
  int ic = icb*32 + (l >> 4)*8 + j;
  float v = (ocr < 3) ? w[(ocr*128 + ic)*16 + kh*4 + kw] : 0.f;
  f[i] = f2bf(v);
}
// CBF[codeT32][kst2][...], hi+lo
__global__ __launch_bounds__(256) void k_cbf(const float* __restrict__ cb,
                                             ushort* __restrict__ fh, ushort* __restrict__ fl){
  int i = blockIdx.x*256 + threadIdx.x;            // 32768
  if (i >= 32768) return;
  int j = i & 7, l = (i >> 3) & 63, rest = i >> 9;
  int kst = rest & 1, cT = rest >> 1;
  int code = cT*16 + (l & 15);
  int d = kst*32 + (l >> 4)*8 + j;
  float v = cb[code*64 + d];
  ushort h = f2bf(v);
  fh[i] = h; fl[i] = f2bf(v - bf2f(h));
}
// code norms
__global__ __launch_bounds__(256) void k_cn(const float* __restrict__ cb,
                                            float* __restrict__ cn){
  int c = blockIdx.x*256 + threadIdx.x;
  if (c >= 512) return;
  const float* p = cb + c*64;
  float s = 0.f;
  #pragma unroll
  for (int d = 0; d < 64; d += 4){
    float4 u = *(const float4*)(p + d);
    s = fmaf(u.x,u.x, fmaf(u.y,u.y, fmaf(u.z,u.z, fmaf(u.w,u.w, s))));
  }
  cn[c] = s;
}

// ---- conv1: x[16,3,256,256] -> H1 f32 NHWC [16][128][128][128] ------------
// block = (b, oh); lane = oc; wave-uniform scalar x reads; coalesced stores.
__global__ __launch_bounds__(256) void k_conv1(const float* __restrict__ x,
                                               const float* __restrict__ w,
                                               const float* __restrict__ bias,
                                               float* __restrict__ h1){
  int t = threadIdx.x;
  int oc = t & 127, owg = t >> 7;
  int bid = blockIdx.x;
  int oh = bid & 127, b = bid >> 7;
  float wv[48];
  const float* wp = w + oc*48;
  #pragma unroll
  for (int i = 0; i < 48; i += 4){
    float4 u = *(const float4*)(wp + i);
    wv[i] = u.x; wv[i+1] = u.y; wv[i+2] = u.z; wv[i+3] = u.w;
  }
  float bv = bias[oc];
  const float* xb = x + b*196608;
  for (int oi = 0; oi < 64; oi++){
    int ow = owg*64 + oi;
    float acc = bv;
    #pragma unroll
    for (int c = 0; c < 3; c++){
      #pragma unroll
      for (int kh = 0; kh < 4; kh++){
        int ih = oh*2 - 1 + kh;
        if ((unsigned)ih >= 256u) continue;
        const float* row = xb + c*65536 + ih*256;
        #pragma unroll
        for (int kw = 0; kw < 4; kw++){
          int iw = ow*2 - 1 + kw;
          if ((unsigned)iw >= 256u) continue;
          acc = fmaf(row[iw], wv[c*16 + kh*4 + kw], acc);
        }
      }
    }
    h1[((b*128 + oh)*128 + ow)*128 + oc] = frelu(acc);
  }
}

// ---- conv2: H1 -> H2 hi/lo, k4 s2 p1, relu, split-3 MFMA ------------------
// tile 16x8 out, all 256 oc; wave = 64 oc x 128 pos.  R=34 C=18.
__global__ __launch_bounds__(256,2) void k_conv2(const float* __restrict__ x,
    const ushort* __restrict__ wfh, const ushort* __restrict__ wfl,
    const float* __restrict__ bias,
    ushort* __restrict__ yh, ushort* __restrict__ yl){
  __shared__ ushort Xs[2*2448*8];                  // hi plane, lo plane (78336B)
  int t = threadIdx.x;
  int li = t & 15, g4 = (t >> 4) & 3, lane = t & 63, wq = t >> 6;
  int bid = blockIdx.x;
  int tile = bid & 31, b = bid >> 5;
  int OH0 = (tile >> 3)*16, OW0 = (tile & 7)*8;
  int ih0 = OH0*2 - 1, iw0 = OW0*2 - 1;
  f32x4 acc[4][8];
  #pragma unroll
  for (int m = 0; m < 4; m++)
    #pragma unroll
    for (int n = 0; n < 8; n++) acc[m][n] = (f32x4){0.f,0.f,0.f,0.f};

  int rb = (li >> 3)*2, cb2 = (li & 7)*2;

  for (int icb = 0; icb < 4; icb++){
    __syncthreads();
    for (int e = t; e < 2448; e += 256){
      int gq = e / 612, cell = e - gq*612;
      int r = cell / 18, c = cell - r*18;
      int ih = ih0 + r, iw = iw0 + c;
      float v[8];
      if ((unsigned)ih < 128u && (unsigned)iw < 128u){
        const float* p = x + ((b*128 + ih)*128 + iw)*128 + icb*32 + gq*8;
        float4 u0 = *(const float4*)p, u1 = *(const float4*)(p + 4);
        v[0]=u0.x; v[1]=u0.y; v[2]=u0.z; v[3]=u0.w;
        v[4]=u1.x; v[5]=u1.y; v[6]=u1.z; v[7]=u1.w;
      } else {
        #pragma unroll
        for (int j = 0; j < 8; j++) v[j] = 0.f;
      }
      bf16x8 h8, l8;
      #pragma unroll
      for (int j = 0; j < 8; j++){
        ushort h = f2bf(v[j]);
        h8[j] = (short)h;
        l8[j] = (short)f2bf(v[j] - bf2f(h));
      }
      *(bf16x8*)(Xs + e*8) = h8;
      *(bf16x8*)(Xs + (2448 + e)*8) = l8;
    }
    __syncthreads();
    for (int khw = 0; khw < 16; khw++){
      int kh = khw >> 2, kw = khw & 3;
      const ushort* aph = wfh + ((khw*4 + icb)*16)*512 + lane*8;
      const ushort* apl = wfl + ((khw*4 + icb)*16)*512 + lane*8;
      bf16x8 Ah[4], Al[4];
      #pragma unroll
      for (int m = 0; m < 4; m++){
        Ah[m] = *(const bf16x8*)(aph + (wq*4 + m)*512);
        Al[m] = *(const bf16x8*)(apl + (wq*4 + m)*512);
      }
      int base0 = g4*612 + (rb + kh)*18 + cb2 + kw;
      #pragma unroll
      for (int n = 0; n < 8; n++){
        int gran = base0 + n*72;
        bf16x8 Bh = *(const bf16x8*)(Xs + gran*8);
        bf16x8 Bl = *(const bf16x8*)(Xs + (2448 + gran)*8);
        #pragma unroll
        for (int m = 0; m < 4; m++){
          acc[m][n] = MFMA16(Ah[m], Bh, acc[m][n]);
          acc[m][n] = MFMA16(Al[m], Bh, acc[m][n]);
          acc[m][n] = MFMA16(Ah[m], Bl, acc[m][n]);
        }
      }
    }
  }
  #pragma unroll
  for (int m = 0; m < 4; m++){
    f32x4 bv = *(const f32x4*)(bias + wq*64 + m*16 + g4*4);
    #pragma unroll
    for (int n = 0; n < 8; n++){
      int oh = OH0 + 2*n + (li >> 3);
      int ow = OW0 + (li & 7);
      int off = ((b*64 + oh)*64 + ow)*256 + wq*64 + m*16 + g4*4;
      s16x4 h4, l4;
      #pragma unroll
      for (int r = 0; r < 4; r++){
        float v = frelu(acc[m][n][r] + bv[r]);
        ushort h = f2bf(v);
        h4[r] = (short)h;
        l4[r] = (short)f2bf(v - bf2f(h));
      }
      *(s16x4*)(yh + off) = h4;
      *(s16x4*)(yl + off) = l4;
    }
  }
}

// ---- conv3: H2 hi/lo -> ZF f32 [65536][64], k3 s1 p1, split-3 MFMA --------
// tile 16x32, 64 oc (all waves); wave = 64 oc x 128 pos.  R=18 C=34.
__global__ __launch_bounds__(256,2) void k_conv3(const ushort* __restrict__ xh,
    const ushort* __restrict__ xl,
    const ushort* __restrict__ wfh, const ushort* __restrict__ wfl,
    const float* __restrict__ bias, float* __restrict__ zf){
  __shared__ ushort Xs[2*2448*8];
  int t = threadIdx.x;
  int li = t & 15, g4 = (t >> 4) & 3, lane = t & 63, wq = t >> 6;
  int bid = blockIdx.x;
  int tile = bid & 7, b = bid >> 3;
  int OH0 = (tile >> 1)*16, OW0 = (tile & 1)*32;
  f32x4 acc[4][8];
  #pragma unroll
  for (int m = 0; m < 4; m++)
    #pragma unroll
    for (int n = 0; n < 8; n++) acc[m][n] = (f32x4){0.f,0.f,0.f,0.f};

  for (int icb = 0; icb < 8; icb++){
    __syncthreads();
    for (int e = t; e < 2448; e += 256){
      int gq = e / 612, cell = e - gq*612;
      int r = cell / 34, c = cell - r*34;
      int ih = OH0 - 1 + r, iw = OW0 - 1 + c;
      bf16x8 vh = {0,0,0,0,0,0,0,0}, vl = {0,0,0,0,0,0,0,0};
      if ((unsigned)ih < 64u && (unsigned)iw < 64u){
        int off = ((b*64 + ih)*64 + iw)*256 + icb*32 + gq*8;
        vh = *(const bf16x8*)(xh + off);
        vl = *(const bf16x8*)(xl + off);
      }
      *(bf16x8*)(Xs + e*8) = vh;
      *(bf16x8*)(Xs + (2448 + e)*8) = vl;
    }
    __syncthreads();
    #pragma unroll
    for (int kh = 0; kh < 3; kh++){
      #pragma unroll
      for (int kw = 0; kw < 3; kw++){
        int khw = kh*3 + kw;
        const ushort* aph = wfh + ((khw*8 + icb)*4)*512 + lane*8;
        const ushort* apl = wfl + ((khw*8 + icb)*4)*512 + lane*8;
        bf16x8 Ah[4], Al[4];
        #pragma unroll
        for (int m = 0; m < 4; m++){
          Ah[m] = *(const bf16x8*)(aph + m*512);
          Al[m] = *(const bf16x8*)(apl + m*512);
        }
        #pragma unroll
        for (int n = 0; n < 8; n++){
          int gran = g4*612 + (wq*4 + (n >> 1) + kh)*34 + (n & 1)*16 + li + kw;
          bf16x8 Bh = *(const bf16x8*)(Xs + gran*8);
          bf16x8 Bl = *(const bf16x8*)(Xs + (2448 + gran)*8);
          #pragma unroll
          for (int m = 0; m < 4; m++){
            acc[m][n] = MFMA16(Ah[m], Bh, acc[m][n]);
            acc[m][n] = MFMA16(Al[m], Bh, acc[m][n]);
            acc[m][n] = MFMA16(Ah[m], Bl, acc[m][n]);
          }
        }
      }
    }
  }
  #pragma unroll
  for (int m = 0; m < 4; m++){
    f32x4 bv = *(const f32x4*)(bias + m*16 + g4*4);
    #pragma unroll
    for (int n = 0; n < 8; n++){
      int oh = OH0 + wq*4 + (n >> 1);
      int ow = OW0 + (n & 1)*16 + li;
      int nIdx = (b*64 + oh)*64 + ow;
      f32x4 v = acc[m][n] + bv;
      *(f32x4*)(zf + nIdx*64 + m*16 + g4*4) = v;
    }
  }
}

// ---- vqdist: argmin over 512 codes via split-3 MFMA -----------------------
__global__ __launch_bounds__(256) void k_vqdist(const float* __restrict__ zf,
    const ushort* __restrict__ cfh, const ushort* __restrict__ cfl,
    const float* __restrict__ cn, int* __restrict__ idxOut){
  int t = threadIdx.x;
  int lane = t & 63, wq = t >> 6;
  int li = lane & 15, g = lane >> 4;
  int rowBase = blockIdx.x*64 + wq*16;
  bf16x8 Bh[2], Bl[2];
  const float* zp = zf + (rowBase + li)*64 + g*8;
  #pragma unroll
  for (int kst = 0; kst < 2; kst++){
    float4 u0 = *(const float4*)(zp + kst*32);
    float4 u1 = *(const float4*)(zp + kst*32 + 4);
    float v[8] = {u0.x,u0.y,u0.z,u0.w,u1.x,u1.y,u1.z,u1.w};
    #pragma unroll
    for (int j = 0; j < 8; j++){
      ushort h = f2bf(v[j]);
      Bh[kst][j] = (short)h;
      Bl[kst][j] = (short)f2bf(v[j] - bf2f(h));
    }
  }
  float best = 3.4e38f; int bi = 0;
  for (int ch = 0; ch < 8; ch++){
    f32x4 acc[4];
    #pragma unroll
    for (int m = 0; m < 4; m++) acc[m] = (f32x4){0.f,0.f,0.f,0.f};
    #pragma unroll
    for (int kst = 0; kst < 2; kst++){
      #pragma unroll
      for (int m = 0; m < 4; m++){
        int cT = ch*4 + m;
        bf16x8 Ah = *(const bf16x8*)(cfh + (cT*2 + kst)*512 + lane*8);
        bf16x8 Al = *(const bf16x8*)(cfl + (cT*2 + kst)*512 + lane*8);
        acc[m] = MFMA16(Ah, Bh[kst], acc[m]);
        acc[m] = MFMA16(Al, Bh[kst], acc[m]);
        acc[m] = MFMA16(Ah, Bl[kst], acc[m]);
      }
    }
    #pragma unroll
    for (int m = 0; m < 4; m++){
      #pragma unroll
      for (int r = 0; r < 4; r++){
        int code = (ch*4 + m)*16 + g*4 + r;
        float d2 = cn[code] - 2.f*acc[m][r];
        if (d2 < best){ best = d2; bi = code; }
      }
    }
  }
  #pragma unroll
  for (int off = 32; off >= 16; off >>= 1){
    float ob = __shfl_down(best, off);
    int oi = __shfl_down(bi, off);
    if (ob < best || (ob == best && oi < bi)){ best = ob; bi = oi; }
  }
  if (lane < 16) idxOut[rowBase + li] = bi;
}

// ---- vqgather: q write (bf16) + vq loss -----------------------------------
__global__ __launch_bounds__(256) void k_vqgather(const float* __restrict__ zf,
    const float* __restrict__ cb, const int* __restrict__ idx,
    ushort* __restrict__ qx, float* __restrict__ lossp){
  int n = blockIdx.x*256 + threadIdx.x;
  int code = idx[n];
  const float* cp = cb + code*64;
  const float* zp = zf + n*64;
  float ls = 0.f;
  #pragma unroll
  for (int d = 0; d < 64; d += 4){
    float4 qv = *(const float4*)(cp + d);
    float4 zv = *(const float4*)(zp + d);
    float d0 = qv.x - zv.x, d1 = qv.y - zv.y, d2 = qv.z - zv.z, d3 = qv.w - zv.w;
    ls = fmaf(d0,d0, fmaf(d1,d1, fmaf(d2,d2, fmaf(d3,d3, ls))));
    s16x4 q4;
    q4[0] = (short)f2bf(qv.x); q4[1] = (short)f2bf(qv.y);
    q4[2] = (short)f2bf(qv.z); q4[3] = (short)f2bf(qv.w);
    *(s16x4*)(qx + n*64 + d) = q4;
  }
  #pragma unroll
  for (int off = 32; off > 0; off >>= 1) ls += __shfl_down(ls, off);
  if ((threadIdx.x & 63) == 0) atomicAdd(lossp, ls * (1.25f/4194304.f));
}

// ---- dec1: QX -> D1, k3 s1 p1, relu, single MFMA --------------------------
// tile 16x8, 256 oc; wave = 128 oc x 64 pos.  R=18 C=10.
__global__ __launch_bounds__(256,2) void k_dec1(const ushort* __restrict__ xq,
    const ushort* __restrict__ wf, const float* __restrict__ bias,
    ushort* __restrict__ y){
  __shared__ ushort Xs[720*8];                     // 11520B
  int t = threadIdx.x;
  int li = t & 15, g4 = (t >> 4) & 3, lane = t & 63, wq = t >> 6;
  int och = wq >> 1, ph = wq & 1;
  int bid = blockIdx.x;
  int tile = bid & 31, b = bid >> 5;
  int OH0 = (tile >> 3)*16, OW0 = (tile & 7)*8;
  f32x4 acc[8][4];
  #pragma unroll
  for (int m = 0; m < 8; m++)
    #pragma unroll
    for (int n = 0; n < 4; n++) acc[m][n] = (f32x4){0.f,0.f,0.f,0.f};

  for (int icb = 0; icb < 2; icb++){
    __syncthreads();
    for (int e = t; e < 720; e += 256){
      int gq = e / 180, cell = e - gq*180;
      int r = cell / 10, c = cell - r*10;
      int ih = OH0 - 1 + r, iw = OW0 - 1 + c;
      bf16x8 v = {0,0,0,0,0,0,0,0};
      if ((unsigned)ih < 64u && (unsigned)iw < 64u)
        v = *(const bf16x8*)(xq + ((b*64 + ih)*64 + iw)*64 + icb*32 + gq*8);
      *(bf16x8*)(Xs + e*8) = v;
    }
    __syncthreads();
    #pragma unroll
    for (int kh = 0; kh < 3; kh++){
      #pragma unroll
      for (int kw = 0; kw < 3; kw++){
        int khw = kh*3 + kw;
        const ushort* ap = wf + ((khw*2 + icb)*16)*512 + lane*8;
        bf16x8 A[8];
        #pragma unroll
        for (int m = 0; m < 8; m++)
          A[m] = *(const bf16x8*)(ap + (och*8 + m)*512);
        #pragma unroll
        for (int nn = 0; nn < 4; nn++){
          int nT = ph*4 + nn;
          int gran = g4*180 + (nT*2 + (li >> 3) + kh)*10 + (li & 7) + kw;
          bf16x8 B = *(const bf16x8*)(Xs + gran*8);
          #pragma unroll
          for (int m = 0; m < 8; m++)
            acc[m][nn] = MFMA16(A[m], B, acc[m][nn]);
        }
      }
    }
  }
  #pragma unroll
  for (int m = 0; m < 8; m++){
    int oc = och*128 + m*16 + g4*4;
    f32x4 bv = *(const f32x4*)(bias + oc);
    #pragma unroll
    for (int nn = 0; nn < 4; nn++){
      int nT = ph*4 + nn;
      int oh = OH0 + nT*2 + (li >> 3);
      int ow = OW0 + (li & 7);
      s16x4 h4;
      #pragma unroll
      for (int r = 0; r < 4; r++)
        h4[r] = (short)f2bf(frelu(acc[m][nn][r] + bv[r]));
      *(s16x4*)(y + ((b*64 + oh)*64 + ow)*256 + oc) = h4;
    }
  }
}

// ---- deconv2: D1 -> D2, transposed k4 s2 p1, relu, single MFMA ------------
// out tile 16x16; wave = parity class, 128 oc x 64 pos.  R=10 C=10.
__global__ __launch_bounds__(256,2) void k_deconv2(const ushort* __restrict__ xq,
    const ushort* __restrict__ wf, const float* __restrict__ bias,
    ushort* __restrict__ y){
  __shared__ ushort Xs[400*8];                     // 6400B
  int t = threadIdx.x;
  int li = t & 15, g4 = (t >> 4) & 3, lane = t & 63, wq = t >> 6;
  int po = wq >> 1, pw = wq & 1;
  int bid = blockIdx.x;
  int tile = bid & 63, b = bid >> 6;
  int Y0 = (tile >> 3)*8, X0 = (tile & 7)*8;
  f32x4 acc[8][4];
  #pragma unroll
  for (int m = 0; m < 8; m++)
    #pragma unroll
    for (int n = 0; n < 4; n++) acc[m][n] = (f32x4){0.f,0.f,0.f,0.f};

  for (int icb = 0; icb < 8; icb++){
    __syncthreads();
    for (int e = t; e < 400; e += 256){
      int gq = e / 100, cell = e - gq*100;
      int r = cell / 10, c = cell - r*10;
      int ih = Y0 - 1 + r, iw = X0 - 1 + c;
      bf16x8 v = {0,0,0,0,0,0,0,0};
      if ((unsigned)ih < 64u && (unsigned)iw < 64u)
        v = *(const bf16x8*)(xq + ((b*64 + ih)*64 + iw)*256 + icb*32 + gq*8);
      *(bf16x8*)(Xs + e*8) = v;
    }
    __syncthreads();
    #pragma unroll
    for (int dhw = 0; dhw < 4; dhw++){
      int dh = dhw >> 1, dw = dhw & 1;
      const ushort* ap = wf + (((wq*4 + dhw)*8 + icb)*8)*512 + lane*8;
      bf16x8 A[8];
      #pragma unroll
      for (int m = 0; m < 8; m++)
        A[m] = *(const bf16x8*)(ap + m*512);
      #pragma unroll
      for (int nn = 0; nn < 4; nn++){
        int yy = nn*2 + (li >> 3), xx = li & 7;
        int gran = g4*100 + (yy + dh + po)*10 + xx + dw + pw;
        bf16x8 B = *(const bf16x8*)(Xs + gran*8);
        #pragma unroll
        for (int m = 0; m < 8; m++)
          acc[m][nn] = MFMA16(A[m], B, acc[m][nn]);
      }
    }
  }
  #pragma unroll
  for (int m = 0; m < 8; m++){
    int oc = m*16 + g4*4;
    f32x4 bv = *(const f32x4*)(bias + oc);
    #pragma unroll
    for (int nn = 0; nn < 4; nn++){
      int yy = nn*2 + (li >> 3), xx = li & 7;
      int oh = 2*(Y0 + yy) + po, ow = 2*(X0 + xx) + pw;
      s16x4 h4;
      #pragma unroll
      for (int r = 0; r < 4; r++)
        h4[r] = (short)f2bf(frelu(acc[m][nn][r] + bv[r]));
      *(s16x4*)(y + ((b*128 + oh)*128 + ow)*128 + oc) = h4;
    }
  }
}

// ---- deconv3: D2 -> out f32 NCHW, transposed k4 s2 p1, single MFMA (M pad 16)
// out tile 32x32; wave = parity class, 3 oc x 256 pos.  R=18 C=18.
__global__ __launch_bounds__(256,2) void k_deconv3(const ushort* __restrict__ xq,
    const ushort* __restrict__ wf, const float* __restrict__ bias,
    float* __restrict__ out){
  __shared__ ushort Xs[1296*8];                    // 20736B
  int t = threadIdx.x;
  int li = t & 15, g4 = (t >> 4) & 3, lane = t & 63, wq = t >> 6;
  int po = wq >> 1, pw = wq & 1;
  int bid = blockIdx.x;
  int tile = bid & 63, b = bid >> 6;
  int Y0 = (tile >> 3)*16, X0 = (tile & 7)*16;
  f32x4 acc[16];
  #pragma unroll
  for (int n = 0; n < 16; n++) acc[n] = (f32x4){0.f,0.f,0.f,0.f};

  for (int icb = 0; icb < 4; icb++){
    __syncthreads();
    for (int e = t; e < 1296; e += 256){
      int gq = e / 324, cell = e - gq*324;
      int r = cell / 18, c = cell - r*18;
      int ih = Y0 - 1 + r, iw = X0 - 1 + c;
      bf16x8 v = {0,0,0,0,0,0,0,0};
      if ((unsigned)ih < 128u && (unsigned)iw < 128u)
        v = *(const bf16x8*)(xq + ((b*128 + ih)*128 + iw)*128 + icb*32 + gq*8);
      *(bf16x8*)(Xs + e*8) = v;
    }
    __syncthreads();
    #pragma unroll
    for (int dhw = 0; dhw < 4; dhw++){
      int dh = dhw >> 1, dw = dhw & 1;
      bf16x8 A = *(const bf16x8*)(wf + ((wq*4 + icb)*4 + dhw)*512 + lane*8);
      #pragma unroll
      for (int n = 0; n < 16; n++){
        int gran = g4*324 + (n + dh + po)*18 + li + dw + pw;
        bf16x8 B = *(const bf16x8*)(Xs + gran*8);
        acc[n] = MFMA16(A, B, acc[n]);
      }
    }
  }
  if (g4 == 0){
    float b0 = bias[0], b1 = bias[1], b2 = bias[2];
    #pragma unroll
    for (int n = 0; n < 16; n++){
      int oh = 2*(Y0 + n) + po, ow = 2*(X0 + li) + pw;
      int base = b*196608 + oh*256 + ow;
      out[base]           = acc[n][0] + b0;
      out[base + 65536]   = acc[n][1] + b1;
      out[base + 131072]  = acc[n][2] + b2;
    }
  }
}

// ---------------------------------------------------------------------------
extern "C" void kernel_launch(void* const* d_in, const int* in_sizes, int n_in,
                              void* d_out, int out_size, void* d_ws, size_t ws_size,
                              hipStream_t stream){
  (void)in_sizes; (void)n_in; (void)out_size; (void)ws_size;
  const float* x   = (const float*)d_in[0];
  const float* ew1 = (const float*)d_in[1];
  const float* eb1 = (const float*)d_in[2];
  const float* ew2 = (const float*)d_in[3];
  const float* eb2 = (const float*)d_in[4];
  const float* ew3 = (const float*)d_in[5];
  const float* eb3 = (const float*)d_in[6];
  const float* cb  = (const float*)d_in[7];
  const float* dw1 = (const float*)d_in[8];
  const float* db1 = (const float*)d_in[9];
  const float* dw2 = (const float*)d_in[10];
  const float* db2 = (const float*)d_in[11];
  const float* dw3 = (const float*)d_in[12];
  const float* db3 = (const float*)d_in[13];
  float* out = (float*)d_out;
  char* w = (char*)d_ws;

  float*  H1   = (float*)(w + 0);
  ushort* H2H  = (ushort*)(w + 134217728);
  ushort* H2L  = (ushort*)(w + 167772160);
  ushort* QX   = (ushort*)(w + 134217728);   // reuse (after conv3)
  ushort* D1   = (ushort*)(w + 0);           // reuse (after conv2)
  ushort* D2   = (ushort*)(w + 150994944);
  float*  ZF   = (float*)(w + 201326592);
  int*    IDX  = (int*)(w + 218103808);
  ushort* W2FH = (ushort*)(w + 218365952);
  ushort* W2FL = (ushort*)(w + 219414528);
  ushort* W3FH = (ushort*)(w + 220463104);
  ushort* W3FL = (ushort*)(w + 220758016);
  ushort* W5F  = (ushort*)(w + 221052928);
  ushort* W6F  = (ushort*)(w + 221347840);
  ushort* W7F  = (ushort*)(w + 222396416);
  ushort* CBFH = (ushort*)(w + 222461952);
  ushort* CBFL = (ushort*)(w + 222527488);
  float*  CN   = (float*)(w + 222593024);

  k_w2f<<<2048, 256, 0, stream>>>(ew2, W2FH, W2FL);
  k_w3f<<<576,  256, 0, stream>>>(ew3, W3FH, W3FL);
  k_w5f<<<576,  256, 0, stream>>>(dw1, W5F);
  k_w6f<<<2048, 256, 0, stream>>>(dw2, W6F);
  k_w7f<<<128,  256, 0, stream>>>(dw3, W7F);
  k_cbf<<<128,  256, 0, stream>>>(cb, CBFH, CBFL);
  k_cn<<<2,     256, 0, stream>>>(cb, CN);
  k_zero1<<<1, 1, 0, stream>>>(out + 3145728);

  k_conv1<<<2048, 256, 0, stream>>>(x, ew1, eb1, H1);
  k_conv2<<<512,  256, 0, stream>>>(H1, W2FH, W2FL, eb2, H2H, H2L);
  k_conv3<<<128,  256, 0, stream>>>(H2H, H2L, W3FH, W3FL, eb3, ZF);
  k_vqdist<<<1024, 256, 0, stream>>>(ZF, CBFH, CBFL, CN, IDX);
  k_vqgather<<<256, 256, 0, stream>>>(ZF, cb, IDX, QX, out + 3145728);
  k_dec1<<<512,   256, 0, stream>>>(QX, W5F, db1, D1);
  k_deconv2<<<1024, 256, 0, stream>>>(D1, W6F, db2, D2);
  k_deconv3<<<1024, 256, 0, stream>>>(D2, W7F, db3, out);
}

// Round 6
// 1224.950 us; speedup vs baseline: 3.6139x; 1.0166x over previous
//
#include <hip/hip_runtime.h>

// ---------------------------------------------------------------------------
// VQ-VAE forward (r5): conv1 reverted to EXACT fp32 chain (bit-identical to
// the r3 passing kernel) but restructured for throughput; it emits H1 as
// hi/lo bf16 planes (same f2bf decomposition r3's conv2 staging applied, so
// the whole encoder+VQ pipeline is bit-identical to r3 -> same argmins).
// Encoder conv2/conv3 + VQ distances: split-bf16 3-product MFMA.
// Decoder dec1/deconv2/deconv3: single bf16 MFMA.
//
// MFMA 16x16x32 bf16 fragments (gfx950, learn_hip m89-verified):
//   A[m][k]: lane l, j -> A[l&15][(l>>4)*8 + j]
//   B[k][n]: lane l, j -> B[(l>>4)*8 + j][l&15]
//   D[m][n]: lane l, r -> D[(l>>4)*4 + r][l&15]
//
// Workspace (byte offsets):
//   H1H bf16 NHWC [16][128][128][128]  @ 0          (67,108,864)
//   H1L bf16                           @ 67108864   (67,108,864)
//   D1  bf16 NHWC [16][64][64][256]    @ 0          (reuse after conv2)
//   H2H bf16 NHWC [16][64][64][256]    @ 134217728  (33,554,432)
//   H2L bf16                           @ 167772160  (33,554,432)
//   QX  bf16 NHWC [16][64][64][64]     @ 134217728  (reuse after conv3)
//   D2  bf16 NHWC [16][128][128][128]  @ 150994944  (33,554,432)
//   ZF  f32 [65536][64]                @ 201326592  (16,777,216)
//   IDX int32 [65536]                  @ 218103808  (262,144)
//   weight frag buffers                @ 218365952
// ---------------------------------------------------------------------------

typedef __attribute__((ext_vector_type(8))) short bf16x8;
typedef __attribute__((ext_vector_type(4))) short s16x4;
typedef __attribute__((ext_vector_type(4))) float f32x4;

#define MFMA16(a,b,c) __builtin_amdgcn_mfma_f32_16x16x32_bf16(a,b,c,0,0,0)

__device__ __forceinline__ ushort f2bf(float f){
  uint u = __float_as_uint(f);
  return (ushort)((u + 0x7fffu + ((u >> 16) & 1u)) >> 16);
}
__device__ __forceinline__ float bf2f(ushort h){
  return __uint_as_float(((uint)h) << 16);
}
__device__ __forceinline__ float frelu(float v){ return v > 0.f ? v : 0.f; }

__global__ void k_zero1(float* p){ *p = 0.f; }

// ---------------- weight prep kernels --------------------------------------
// W2F[khw16][icb4][ocT16][lane64][j8], hi+lo
__global__ __launch_bounds__(256) void k_w2f(const float* __restrict__ w,
                                             ushort* __restrict__ fh, ushort* __restrict__ fl){
  int i = blockIdx.x*256 + threadIdx.x;            // 524288
  int j = i & 7, l = (i >> 3) & 63, rest = i >> 9;
  int ocT = rest & 15, icb = (rest >> 4) & 3, khw = rest >> 6;
  int oc = ocT*16 + (l & 15);
  int ic = icb*32 + (l >> 4)*8 + j;
  float v = w[(oc*128 + ic)*16 + khw];
  ushort h = f2bf(v);
  fh[i] = h; fl[i] = f2bf(v - bf2f(h));
}
// W3F[khw9][icb8][ocT4][...], hi+lo
__global__ __launch_bounds__(256) void k_w3f(const float* __restrict__ w,
                                             ushort* __restrict__ fh, ushort* __restrict__ fl){
  int i = blockIdx.x*256 + threadIdx.x;            // 147456
  if (i >= 147456) return;
  int j = i & 7, l = (i >> 3) & 63, rest = i >> 9;
  int ocT = rest & 3, r2 = rest >> 2;
  int icb = r2 & 7, khw = r2 >> 3;
  int oc = ocT*16 + (l & 15);
  int ic = icb*32 + (l >> 4)*8 + j;
  float v = w[(oc*256 + ic)*9 + khw];
  ushort h = f2bf(v);
  fh[i] = h; fl[i] = f2bf(v - bf2f(h));
}
// W5F[khw9][icb2][ocT16][...], single
__global__ __launch_bounds__(256) void k_w5f(const float* __restrict__ w,
                                             ushort* __restrict__ f){
  int i = blockIdx.x*256 + threadIdx.x;            // 147456
  if (i >= 147456) return;
  int j = i & 7, l = (i >> 3) & 63, rest = i >> 9;
  int ocT = rest & 15, r2 = rest >> 4;
  int icb = r2 & 1, khw = r2 >> 1;
  int oc = ocT*16 + (l & 15);
  int ic = icb*32 + (l >> 4)*8 + j;
  f[i] = f2bf(w[(oc*64 + ic)*9 + khw]);
}
// W6F[par4][dhw4][icb8][ocT8][...], single
__global__ __launch_bounds__(256) void k_w6f(const float* __restrict__ w,
                                             ushort* __restrict__ f){
  int i = blockIdx.x*256 + threadIdx.x;            // 524288
  int j = i & 7, l = (i >> 3) & 63, rest = i >> 9;
  int ocT = rest & 7, icb = (rest >> 3) & 7, dhw = (rest >> 6) & 3, par = rest >> 8;
  int po = par >> 1, pw = par & 1;
  int kh = po + 2*(dhw >> 1), kw = pw + 2*(dhw & 1);
  int oc = ocT*16 + (l & 15);
  int ic = icb*32 + (l >> 4)*8 + j;
  f[i] = f2bf(w[(oc*256 + ic)*16 + kh*4 + kw]);
}
// W7F[par4][icb4][dhw4][1 ocT pad16][...], single
__global__ __launch_bounds__(256) void k_w7f(const float* __restrict__ w,
                                             ushort* __restrict__ f){
  int i = blockIdx.x*256 + threadIdx.x;            // 32768
  if (i >= 32768) return;
  int j = i & 7, l = (i >> 3) & 63, rest = i >> 9;
  int dhw = rest & 3, icb = (rest >> 2) & 3, par = (rest >> 4) & 3;
  int po = par >> 1, pw = par & 1;
  int kh = po + 2*(dhw >> 1), kw = pw + 2*(dhw & 1);
  int ocr = l & 15;
  int ic = icb*32 + (l >> 4)*8 + j;
  float v = (ocr < 3) ? w[(ocr*128 + ic)*16 + kh*4 + kw] : 0.f;
  f[i] = f2bf(v);
}
// CBF[codeT32][kst2][...], hi+lo
__global__ __launch_bounds__(256) void k_cbf(const float* __restrict__ cb,
                                             ushort* __restrict__ fh, ushort* __restrict__ fl){
  int i = blockIdx.x*256 + threadIdx.x;            // 32768
  if (i >= 32768) return;
  int j = i & 7, l = (i >> 3) & 63, rest = i >> 9;
  int kst = rest & 1, cT = rest >> 1;
  int code = cT*16 + (l & 15);
  int d = kst*32 + (l >> 4)*8 + j;
  float v = cb[code*64 + d];
  ushort h = f2bf(v);
  fh[i] = h; fl[i] = f2bf(v - bf2f(h));
}
// code norms
__global__ __launch_bounds__(256) void k_cn(const float* __restrict__ cb,
                                            float* __restrict__ cn){
  int c = blockIdx.x*256 + threadIdx.x;
  if (c >= 512) return;
  const float* p = cb + c*64;
  float s = 0.f;
  #pragma unroll
  for (int d = 0; d < 64; d += 4){
    float4 u = *(const float4*)(p + d);
    s = fmaf(u.x,u.x, fmaf(u.y,u.y, fmaf(u.z,u.z, fmaf(u.w,u.w, s))));
  }
  cn[c] = s;
}

// ---- conv1 EXACT fp32: x[16,3,256,256] -> H1 hi/lo bf16 NHWC, k4 s2 p1 ----
// Bit-identical arithmetic to the r3 passing kernel: per output, acc=bias,
// then fmaf over (c, kh, kw) in order; OOB taps contribute exact-zero fmaf
// (no-op on acc). 8-ow chunks with 18-float wave-uniform row windows give
// scalar-load ILP instead of r3's serial dependent loads.
__global__ __launch_bounds__(256) void k_conv1(const float* __restrict__ x,
    const float* __restrict__ w, const float* __restrict__ bias,
    ushort* __restrict__ yh, ushort* __restrict__ yl){
  int t = threadIdx.x;
  int oc = t & 127, half = t >> 7;
  int bid = blockIdx.x;
  int oh = bid & 127, b = bid >> 7;
  float wv[48];
  const float* wp = w + oc*48;
  #pragma unroll
  for (int i = 0; i < 48; i += 4){
    float4 u = *(const float4*)(wp + i);
    wv[i] = u.x; wv[i+1] = u.y; wv[i+2] = u.z; wv[i+3] = u.w;
  }
  float bv = bias[oc];
  const float* xb = x + b*196608;
  int ih_base = oh*2 - 1;
  for (int ch = 0; ch < 8; ch++){
    int ow0 = half*64 + ch*8;
    int iwb = ow0*2 - 1;
    float acc[8];
    #pragma unroll
    for (int i = 0; i < 8; i++) acc[i] = bv;
    #pragma unroll
    for (int c = 0; c < 3; c++){
      #pragma unroll
      for (int kh = 0; kh < 4; kh++){
        int ih = ih_base + kh;
        float xr[18];
        if ((unsigned)ih < 256u){
          const float* row = xb + c*65536 + ih*256;
          #pragma unroll
          for (int k2 = 0; k2 < 18; k2++){
            int iw = iwb + k2;
            xr[k2] = ((unsigned)iw < 256u) ? row[iw] : 0.f;
          }
        } else {
          #pragma unroll
          for (int k2 = 0; k2 < 18; k2++) xr[k2] = 0.f;
        }
        #pragma unroll
        for (int i = 0; i < 8; i++){
          #pragma unroll
          for (int kw = 0; kw < 4; kw++)
            acc[i] = fmaf(xr[2*i + kw], wv[c*16 + kh*4 + kw], acc[i]);
        }
      }
    }
    #pragma unroll
    for (int i = 0; i < 8; i++){
      float v = frelu(acc[i]);
      ushort h = f2bf(v);
      ushort l = f2bf(v - bf2f(h));
      int off = ((b*128 + oh)*128 + (ow0 + i))*128 + oc;
      yh[off] = h; yl[off] = l;
    }
  }
}

// ---- conv2: H1 hi/lo -> H2 hi/lo, k4 s2 p1, relu, split-3 MFMA ------------
// tile 16x8 out, all 256 oc; wave = 64 oc x 128 pos.  R=34 C=18.
__global__ __launch_bounds__(256,2) void k_conv2(const ushort* __restrict__ xh,
    const ushort* __restrict__ xl,
    const ushort* __restrict__ wfh, const ushort* __restrict__ wfl,
    const float* __restrict__ bias,
    ushort* __restrict__ yh, ushort* __restrict__ yl){
  __shared__ ushort Xs[2*2448*8];                  // hi plane, lo plane (78336B)
  int t = threadIdx.x;
  int li = t & 15, g4 = (t >> 4) & 3, lane = t & 63, wq = t >> 6;
  int bid = blockIdx.x;
  int tile = bid & 31, b = bid >> 5;
  int OH0 = (tile >> 3)*16, OW0 = (tile & 7)*8;
  int ih0 = OH0*2 - 1, iw0 = OW0*2 - 1;
  f32x4 acc[4][8];
  #pragma unroll
  for (int m = 0; m < 4; m++)
    #pragma unroll
    for (int n = 0; n < 8; n++) acc[m][n] = (f32x4){0.f,0.f,0.f,0.f};

  int rb = (li >> 3)*2, cb2 = (li & 7)*2;

  for (int icb = 0; icb < 4; icb++){
    __syncthreads();
    for (int e = t; e < 2448; e += 256){
      int gq = e / 612, cell = e - gq*612;
      int r = cell / 18, c = cell - r*18;
      int ih = ih0 + r, iw = iw0 + c;
      bf16x8 vh = {0,0,0,0,0,0,0,0}, vl = {0,0,0,0,0,0,0,0};
      if ((unsigned)ih < 128u && (unsigned)iw < 128u){
        int off = ((b*128 + ih)*128 + iw)*128 + icb*32 + gq*8;
        vh = *(const bf16x8*)(xh + off);
        vl = *(const bf16x8*)(xl + off);
      }
      *(bf16x8*)(Xs + e*8) = vh;
      *(bf16x8*)(Xs + (2448 + e)*8) = vl;
    }
    __syncthreads();
    for (int khw = 0; khw < 16; khw++){
      int kh = khw >> 2, kw = khw & 3;
      const ushort* aph = wfh + ((khw*4 + icb)*16)*512 + lane*8;
      const ushort* apl = wfl + ((khw*4 + icb)*16)*512 + lane*8;
      bf16x8 Ah[4], Al[4];
      #pragma unroll
      for (int m = 0; m < 4; m++){
        Ah[m] = *(const bf16x8*)(aph + (wq*4 + m)*512);
        Al[m] = *(const bf16x8*)(apl + (wq*4 + m)*512);
      }
      int base0 = g4*612 + (rb + kh)*18 + cb2 + kw;
      #pragma unroll
      for (int n = 0; n < 8; n++){
        int gran = base0 + n*72;
        bf16x8 Bh = *(const bf16x8*)(Xs + gran*8);
        bf16x8 Bl = *(const bf16x8*)(Xs + (2448 + gran)*8);
        #pragma unroll
        for (int m = 0; m < 4; m++){
          acc[m][n] = MFMA16(Ah[m], Bh, acc[m][n]);
          acc[m][n] = MFMA16(Al[m], Bh, acc[m][n]);
          acc[m][n] = MFMA16(Ah[m], Bl, acc[m][n]);
        }
      }
    }
  }
  #pragma unroll
  for (int m = 0; m < 4; m++){
    f32x4 bv = *(const f32x4*)(bias + wq*64 + m*16 + g4*4);
    #pragma unroll
    for (int n = 0; n < 8; n++){
      int oh = OH0 + 2*n + (li >> 3);
      int ow = OW0 + (li & 7);
      int off = ((b*64 + oh)*64 + ow)*256 + wq*64 + m*16 + g4*4;
      s16x4 h4, l4;
      #pragma unroll
      for (int r = 0; r < 4; r++){
        float v = frelu(acc[m][n][r] + bv[r]);
        ushort h = f2bf(v);
        h4[r] = (short)h;
        l4[r] = (short)f2bf(v - bf2f(h));
      }
      *(s16x4*)(yh + off) = h4;
      *(s16x4*)(yl + off) = l4;
    }
  }
}

// ---- conv3: H2 hi/lo -> ZF f32 [65536][64], k3 s1 p1, split-3 MFMA --------
// tile 16x32, 64 oc (all waves); wave = 64 oc x 128 pos.  R=18 C=34.
__global__ __launch_bounds__(256,2) void k_conv3(const ushort* __restrict__ xh,
    const ushort* __restrict__ xl,
    const ushort* __restrict__ wfh, const ushort* __restrict__ wfl,
    const float* __restrict__ bias, float* __restrict__ zf){
  __shared__ ushort Xs[2*2448*8];
  int t = threadIdx.x;
  int li = t & 15, g4 = (t >> 4) & 3, lane = t & 63, wq = t >> 6;
  int bid = blockIdx.x;
  int tile = bid & 7, b = bid >> 3;
  int OH0 = (tile >> 1)*16, OW0 = (tile & 1)*32;
  f32x4 acc[4][8];
  #pragma unroll
  for (int m = 0; m < 4; m++)
    #pragma unroll
    for (int n = 0; n < 8; n++) acc[m][n] = (f32x4){0.f,0.f,0.f,0.f};

  for (int icb = 0; icb < 8; icb++){
    __syncthreads();
    for (int e = t; e < 2448; e += 256){
      int gq = e / 612, cell = e - gq*612;
      int r = cell / 34, c = cell - r*34;
      int ih = OH0 - 1 + r, iw = OW0 - 1 + c;
      bf16x8 vh = {0,0,0,0,0,0,0,0}, vl = {0,0,0,0,0,0,0,0};
      if ((unsigned)ih < 64u && (unsigned)iw < 64u){
        int off = ((b*64 + ih)*64 + iw)*256 + icb*32 + gq*8;
        vh = *(const bf16x8*)(xh + off);
        vl = *(const bf16x8*)(xl + off);
      }
      *(bf16x8*)(Xs + e*8) = vh;
      *(bf16x8*)(Xs + (2448 + e)*8) = vl;
    }
    __syncthreads();
    #pragma unroll
    for (int kh = 0; kh < 3; kh++){
      #pragma unroll
      for (int kw = 0; kw < 3; kw++){
        int khw = kh*3 + kw;
        const ushort* aph = wfh + ((khw*8 + icb)*4)*512 + lane*8;
        const ushort* apl = wfl + ((khw*8 + icb)*4)*512 + lane*8;
        bf16x8 Ah[4], Al[4];
        #pragma unroll
        for (int m = 0; m < 4; m++){
          Ah[m] = *(const bf16x8*)(aph + m*512);
          Al[m] = *(const bf16x8*)(apl + m*512);
        }
        #pragma unroll
        for (int n = 0; n < 8; n++){
          int gran = g4*612 + (wq*4 + (n >> 1) + kh)*34 + (n & 1)*16 + li + kw;
          bf16x8 Bh = *(const bf16x8*)(Xs + gran*8);
          bf16x8 Bl = *(const bf16x8*)(Xs + (2448 + gran)*8);
          #pragma unroll
          for (int m = 0; m < 4; m++){
            acc[m][n] = MFMA16(Ah[m], Bh, acc[m][n]);
            acc[m][n] = MFMA16(Al[m], Bh, acc[m][n]);
            acc[m][n] = MFMA16(Ah[m], Bl, acc[m][n]);
          }
        }
      }
    }
  }
  #pragma unroll
  for (int m = 0; m < 4; m++){
    f32x4 bv = *(const f32x4*)(bias + m*16 + g4*4);
    #pragma unroll
    for (int n = 0; n < 8; n++){
      int oh = OH0 + wq*4 + (n >> 1);
      int ow = OW0 + (n & 1)*16 + li;
      int nIdx = (b*64 + oh)*64 + ow;
      f32x4 v = acc[m][n] + bv;
      *(f32x4*)(zf + nIdx*64 + m*16 + g4*4) = v;
    }
  }
}

// ---- vqdist: argmin over 512 codes via split-3 MFMA -----------------------
__global__ __launch_bounds__(256) void k_vqdist(const float* __restrict__ zf,
    const ushort* __restrict__ cfh, const ushort* __restrict__ cfl,
    const float* __restrict__ cn, int* __restrict__ idxOut){
  int t = threadIdx.x;
  int lane = t & 63, wq = t >> 6;
  int li = lane & 15, g = lane >> 4;
  int rowBase = blockIdx.x*64 + wq*16;
  bf16x8 Bh[2], Bl[2];
  const float* zp = zf + (rowBase + li)*64 + g*8;
  #pragma unroll
  for (int kst = 0; kst < 2; kst++){
    float4 u0 = *(const float4*)(zp + kst*32);
    float4 u1 = *(const float4*)(zp + kst*32 + 4);
    float v[8] = {u0.x,u0.y,u0.z,u0.w,u1.x,u1.y,u1.z,u1.w};
    #pragma unroll
    for (int j = 0; j < 8; j++){
      ushort h = f2bf(v[j]);
      Bh[kst][j] = (short)h;
      Bl[kst][j] = (short)f2bf(v[j] - bf2f(h));
    }
  }
  float best = 3.4e38f; int bi = 0;
  for (int ch = 0; ch < 8; ch++){
    f32x4 acc[4];
    #pragma unroll
    for (int m = 0; m < 4; m++) acc[m] = (f32x4){0.f,0.f,0.f,0.f};
    #pragma unroll
    for (int kst = 0; kst < 2; kst++){
      #pragma unroll
      for (int m = 0; m < 4; m++){
        int cT = ch*4 + m;
        bf16x8 Ah = *(const bf16x8*)(cfh + (cT*2 + kst)*512 + lane*8);
        bf16x8 Al = *(const bf16x8*)(cfl + (cT*2 + kst)*512 + lane*8);
        acc[m] = MFMA16(Ah, Bh[kst], acc[m]);
        acc[m] = MFMA16(Al, Bh[kst], acc[m]);
        acc[m] = MFMA16(Ah, Bl[kst], acc[m]);
      }
    }
    #pragma unroll
    for (int m = 0; m < 4; m++){
      #pragma unroll
      for (int r = 0; r < 4; r++){
        int code = (ch*4 + m)*16 + g*4 + r;
        float d2 = cn[code] - 2.f*acc[m][r];
        if (d2 < best){ best = d2; bi = code; }
      }
    }
  }
  #pragma unroll
  for (int off = 32; off >= 16; off >>= 1){
    float ob = __shfl_down(best, off);
    int oi = __shfl_down(bi, off);
    if (ob < best || (ob == best && oi < bi)){ best = ob; bi = oi; }
  }
  if (lane < 16) idxOut[rowBase + li] = bi;
}

// ---- vqgather: q write (bf16) + vq loss -----------------------------------
__global__ __launch_bounds__(256) void k_vqgather(const float* __restrict__ zf,
    const float* __restrict__ cb, const int* __restrict__ idx,
    ushort* __restrict__ qx, float* __restrict__ lossp){
  int n = blockIdx.x*256 + threadIdx.x;
  int code = idx[n];
  const float* cp = cb + code*64;
  const float* zp = zf + n*64;
  float ls = 0.f;
  #pragma unroll
  for (int d = 0; d < 64; d += 4){
    float4 qv = *(const float4*)(cp + d);
    float4 zv = *(const float4*)(zp + d);
    float d0 = qv.x - zv.x, d1 = qv.y - zv.y, d2 = qv.z - zv.z, d3 = qv.w - zv.w;
    ls = fmaf(d0,d0, fmaf(d1,d1, fmaf(d2,d2, fmaf(d3,d3, ls))));
    s16x4 q4;
    q4[0] = (short)f2bf(qv.x); q4[1] = (short)f2bf(qv.y);
    q4[2] = (short)f2bf(qv.z); q4[3] = (short)f2bf(qv.w);
    *(s16x4*)(qx + n*64 + d) = q4;
  }
  #pragma unroll
  for (int off = 32; off > 0; off >>= 1) ls += __shfl_down(ls, off);
  if ((threadIdx.x & 63) == 0) atomicAdd(lossp, ls * (1.25f/4194304.f));
}

// ---- dec1: QX -> D1, k3 s1 p1, relu, single MFMA --------------------------
// tile 16x8, 256 oc; wave = 128 oc x 64 pos.  R=18 C=10.
__global__ __launch_bounds__(256,2) void k_dec1(const ushort* __restrict__ xq,
    const ushort* __restrict__ wf, const float* __restrict__ bias,
    ushort* __restrict__ y){
  __shared__ ushort Xs[720*8];                     // 11520B
  int t = threadIdx.x;
  int li = t & 15, g4 = (t >> 4) & 3, lane = t & 63, wq = t >> 6;
  int och = wq >> 1, ph = wq & 1;
  int bid = blockIdx.x;
  int tile = bid & 31, b = bid >> 5;
  int OH0 = (tile >> 3)*16, OW0 = (tile & 7)*8;
  f32x4 acc[8][4];
  #pragma unroll
  for (int m = 0; m < 8; m++)
    #pragma unroll
    for (int n = 0; n < 4; n++) acc[m][n] = (f32x4){0.f,0.f,0.f,0.f};

  for (int icb = 0; icb < 2; icb++){
    __syncthreads();
    for (int e = t; e < 720; e += 256){
      int gq = e / 180, cell = e - gq*180;
      int r = cell / 10, c = cell - r*10;
      int ih = OH0 - 1 + r, iw = OW0 - 1 + c;
      bf16x8 v = {0,0,0,0,0,0,0,0};
      if ((unsigned)ih < 64u && (unsigned)iw < 64u)
        v = *(const bf16x8*)(xq + ((b*64 + ih)*64 + iw)*64 + icb*32 + gq*8);
      *(bf16x8*)(Xs + e*8) = v;
    }
    __syncthreads();
    #pragma unroll
    for (int kh = 0; kh < 3; kh++){
      #pragma unroll
      for (int kw = 0; kw < 3; kw++){
        int khw = kh*3 + kw;
        const ushort* ap = wf + ((khw*2 + icb)*16)*512 + lane*8;
        bf16x8 A[8];
        #pragma unroll
        for (int m = 0; m < 8; m++)
          A[m] = *(const bf16x8*)(ap + (och*8 + m)*512);
        #pragma unroll
        for (int nn = 0; nn < 4; nn++){
          int nT = ph*4 + nn;
          int gran = g4*180 + (nT*2 + (li >> 3) + kh)*10 + (li & 7) + kw;
          bf16x8 B = *(const bf16x8*)(Xs + gran*8);
          #pragma unroll
          for (int m = 0; m < 8; m++)
            acc[m][nn] = MFMA16(A[m], B, acc[m][nn]);
        }
      }
    }
  }
  #pragma unroll
  for (int m = 0; m < 8; m++){
    int oc = och*128 + m*16 + g4*4;
    f32x4 bv = *(const f32x4*)(bias + oc);
    #pragma unroll
    for (int nn = 0; nn < 4; nn++){
      int nT = ph*4 + nn;
      int oh = OH0 + nT*2 + (li >> 3);
      int ow = OW0 + (li & 7);
      s16x4 h4;
      #pragma unroll
      for (int r = 0; r < 4; r++)
        h4[r] = (short)f2bf(frelu(acc[m][nn][r] + bv[r]));
      *(s16x4*)(y + ((b*64 + oh)*64 + ow)*256 + oc) = h4;
    }
  }
}

// ---- deconv2: D1 -> D2, transposed k4 s2 p1, relu, single MFMA ------------
// out tile 16x16; wave = parity class, 128 oc x 64 pos.  R=10 C=10.
__global__ __launch_bounds__(256,2) void k_deconv2(const ushort* __restrict__ xq,
    const ushort* __restrict__ wf, const float* __restrict__ bias,
    ushort* __restrict__ y){
  __shared__ ushort Xs[400*8];                     // 6400B
  int t = threadIdx.x;
  int li = t & 15, g4 = (t >> 4) & 3, lane = t & 63, wq = t >> 6;
  int po = wq >> 1, pw = wq & 1;
  int bid = blockIdx.x;
  int tile = bid & 63, b = bid >> 6;
  int Y0 = (tile >> 3)*8, X0 = (tile & 7)*8;
  f32x4 acc[8][4];
  #pragma unroll
  for (int m = 0; m < 8; m++)
    #pragma unroll
    for (int n = 0; n < 4; n++) acc[m][n] = (f32x4){0.f,0.f,0.f,0.f};

  for (int icb = 0; icb < 8; icb++){
    __syncthreads();
    for (int e = t; e < 400; e += 256){
      int gq = e / 100, cell = e - gq*100;
      int r = cell / 10, c = cell - r*10;
      int ih = Y0 - 1 + r, iw = X0 - 1 + c;
      bf16x8 v = {0,0,0,0,0,0,0,0};
      if ((unsigned)ih < 64u && (unsigned)iw < 64u)
        v = *(const bf16x8*)(xq + ((b*64 + ih)*64 + iw)*256 + icb*32 + gq*8);
      *(bf16x8*)(Xs + e*8) = v;
    }
    __syncthreads();
    #pragma unroll
    for (int dhw = 0; dhw < 4; dhw++){
      int dh = dhw >> 1, dw = dhw & 1;
      const ushort* ap = wf + (((wq*4 + dhw)*8 + icb)*8)*512 + lane*8;
      bf16x8 A[8];
      #pragma unroll
      for (int m = 0; m < 8; m++)
        A[m] = *(const bf16x8*)(ap + m*512);
      #pragma unroll
      for (int nn = 0; nn < 4; nn++){
        int yy = nn*2 + (li >> 3), xx = li & 7;
        int gran = g4*100 + (yy + dh + po)*10 + xx + dw + pw;
        bf16x8 B = *(const bf16x8*)(Xs + gran*8);
        #pragma unroll
        for (int m = 0; m < 8; m++)
          acc[m][nn] = MFMA16(A[m], B, acc[m][nn]);
      }
    }
  }
  #pragma unroll
  for (int m = 0; m < 8; m++){
    int oc = m*16 + g4*4;
    f32x4 bv = *(const f32x4*)(bias + oc);
    #pragma unroll
    for (int nn = 0; nn < 4; nn++){
      int yy = nn*2 + (li >> 3), xx = li & 7;
      int oh = 2*(Y0 + yy) + po, ow = 2*(X0 + xx) + pw;
      s16x4 h4;
      #pragma unroll
      for (int r = 0; r < 4; r++)
        h4[r] = (short)f2bf(frelu(acc[m][nn][r] + bv[r]));
      *(s16x4*)(y + ((b*128 + oh)*128 + ow)*128 + oc) = h4;
    }
  }
}

// ---- deconv3: D2 -> out f32 NCHW, transposed k4 s2 p1, single MFMA (M pad 16)
// out tile 32x32; wave = parity class, 3 oc x 256 pos.  R=18 C=18.
__global__ __launch_bounds__(256,2) void k_deconv3(const ushort* __restrict__ xq,
    const ushort* __restrict__ wf, const float* __restrict__ bias,
    float* __restrict__ out){
  __shared__ ushort Xs[1296*8];                    // 20736B
  int t = threadIdx.x;
  int li = t & 15, g4 = (t >> 4) & 3, lane = t & 63, wq = t >> 6;
  int po = wq >> 1, pw = wq & 1;
  int bid = blockIdx.x;
  int tile = bid & 63, b = bid >> 6;
  int Y0 = (tile >> 3)*16, X0 = (tile & 7)*16;
  f32x4 acc[16];
  #pragma unroll
  for (int n = 0; n < 16; n++) acc[n] = (f32x4){0.f,0.f,0.f,0.f};

  for (int icb = 0; icb < 4; icb++){
    __syncthreads();
    for (int e = t; e < 1296; e += 256){
      int gq = e / 324, cell = e - gq*324;
      int r = cell / 18, c = cell - r*18;
      int ih = Y0 - 1 + r, iw = X0 - 1 + c;
      bf16x8 v = {0,0,0,0,0,0,0,0};
      if ((unsigned)ih < 128u && (unsigned)iw < 128u)
        v = *(const bf16x8*)(xq + ((b*128 + ih)*128 + iw)*128 + icb*32 + gq*8);
      *(bf16x8*)(Xs + e*8) = v;
    }
    __syncthreads();
    #pragma unroll
    for (int dhw = 0; dhw < 4; dhw++){
      int dh = dhw >> 1, dw = dhw & 1;
      bf16x8 A = *(const bf16x8*)(wf + ((wq*4 + icb)*4 + dhw)*512 + lane*8);
      #pragma unroll
      for (int n = 0; n < 16; n++){
        int gran = g4*324 + (n + dh + po)*18 + li + dw + pw;
        bf16x8 B = *(const bf16x8*)(Xs + gran*8);
        acc[n] = MFMA16(A, B, acc[n]);
      }
    }
  }
  if (g4 == 0){
    float b0 = bias[0], b1 = bias[1], b2 = bias[2];
    #pragma unroll
    for (int n = 0; n < 16; n++){
      int oh = 2*(Y0 + n) + po, ow = 2*(X0 + li) + pw;
      int base = b*196608 + oh*256 + ow;
      out[base]           = acc[n][0] + b0;
      out[base + 65536]   = acc[n][1] + b1;
      out[base + 131072]  = acc[n][2] + b2;
    }
  }
}

// ---------------------------------------------------------------------------
extern "C" void kernel_launch(void* const* d_in, const int* in_sizes, int n_in,
                              void* d_out, int out_size, void* d_ws, size_t ws_size,
                              hipStream_t stream){
  (void)in_sizes; (void)n_in; (void)out_size; (void)ws_size;
  const float* x   = (const float*)d_in[0];
  const float* ew1 = (const float*)d_in[1];
  const float* eb1 = (const float*)d_in[2];
  const float* ew2 = (const float*)d_in[3];
  const float* eb2 = (const float*)d_in[4];
  const float* ew3 = (const float*)d_in[5];
  const float* eb3 = (const float*)d_in[6];
  const float* cb  = (const float*)d_in[7];
  const float* dw1 = (const float*)d_in[8];
  const float* db1 = (const float*)d_in[9];
  const float* dw2 = (const float*)d_in[10];
  const float* db2 = (const float*)d_in[11];
  const float* dw3 = (const float*)d_in[12];
  const float* db3 = (const float*)d_in[13];
  float* out = (float*)d_out;
  char* w = (char*)d_ws;

  ushort* H1H  = (ushort*)(w + 0);
  ushort* H1L  = (ushort*)(w + 67108864);
  ushort* D1   = (ushort*)(w + 0);           // reuse (after conv2)
  ushort* H2H  = (ushort*)(w + 134217728);
  ushort* H2L  = (ushort*)(w + 167772160);
  ushort* QX   = (ushort*)(w + 134217728);   // reuse (after conv3)
  ushort* D2   = (ushort*)(w + 150994944);
  float*  ZF   = (float*)(w + 201326592);
  int*    IDX  = (int*)(w + 218103808);
  ushort* W2FH = (ushort*)(w + 218365952);
  ushort* W2FL = (ushort*)(w + 219414528);
  ushort* W3FH = (ushort*)(w + 220463104);
  ushort* W3FL = (ushort*)(w + 220758016);
  ushort* W5F  = (ushort*)(w + 221052928);
  ushort* W6F  = (ushort*)(w + 221347840);
  ushort* W7F  = (ushort*)(w + 222396416);
  ushort* CBFH = (ushort*)(w + 222461952);
  ushort* CBFL = (ushort*)(w + 222527488);
  float*  CN   = (float*)(w + 222593024);

  k_w2f<<<2048, 256, 0, stream>>>(ew2, W2FH, W2FL);
  k_w3f<<<576,  256, 0, stream>>>(ew3, W3FH, W3FL);
  k_w5f<<<576,  256, 0, stream>>>(dw1, W5F);
  k_w6f<<<2048, 256, 0, stream>>>(dw2, W6F);
  k_w7f<<<128,  256, 0, stream>>>(dw3, W7F);
  k_cbf<<<128,  256, 0, stream>>>(cb, CBFH, CBFL);
  k_cn<<<2,     256, 0, stream>>>(cb, CN);
  k_zero1<<<1, 1, 0, stream>>>(out + 3145728);

  k_conv1<<<2048, 256, 0, stream>>>(x, ew1, eb1, H1H, H1L);
  k_conv2<<<512,  256, 0, stream>>>(H1H, H1L, W2FH, W2FL, eb2, H2H, H2L);
  k_conv3<<<128,  256, 0, stream>>>(H2H, H2L, W3FH, W3FL, eb3, ZF);
  k_vqdist<<<1024, 256, 0, stream>>>(ZF, CBFH, CBFL, CN, IDX);
  k_vqgather<<<256, 256, 0, stream>>>(ZF, cb, IDX, QX, out + 3145728);
  k_dec1<<<512,   256, 0, stream>>>(QX, W5F, db1, D1);
  k_deconv2<<<1024, 256, 0, stream>>>(D1, W6F, db2, D2);
  k_deconv3<<<1024, 256, 0, stream>>>(D2, W7F, db3, out);
}

// Round 8
// 975.916 us; speedup vs baseline: 4.5361x; 1.2552x over previous
//
#include <hip/hip_runtime.h>

// ---------------------------------------------------------------------------
// VQ-VAE forward (r7):
//  - conv1: exact fp32 (bit-identical chain) with LDS row staging; VGPR ~96.
//  - conv2: parity-deinterleaved LDS (stride-2 bank-conflict fix).
// Encoder conv2/conv3 + VQ distances: split-bf16 3-product MFMA.
// Decoder dec1/deconv2/deconv3: single bf16 MFMA.
//
// MFMA 16x16x32 bf16 fragments (gfx950, learn_hip m89-verified):
//   A[m][k]: lane l, j -> A[l&15][(l>>4)*8 + j]
//   B[k][n]: lane l, j -> B[(l>>4)*8 + j][l&15]
//   D[m][n]: lane l, r -> D[(l>>4)*4 + r][l&15]
//
// Workspace (byte offsets):
//   H1H bf16 NHWC [16][128][128][128]  @ 0          (67,108,864)
//   H1L bf16                           @ 67108864   (67,108,864)
//   D1  bf16 NHWC [16][64][64][256]    @ 0          (reuse after conv2)
//   H2H bf16 NHWC [16][64][64][256]    @ 134217728  (33,554,432)
//   H2L bf16                           @ 167772160  (33,554,432)
//   QX  bf16 NHWC [16][64][64][64]     @ 134217728  (reuse after conv3)
//   D2  bf16 NHWC [16][128][128][128]  @ 150994944  (33,554,432)
//   ZF  f32 [65536][64]                @ 201326592  (16,777,216)
//   IDX int32 [65536]                  @ 218103808  (262,144)
//   weight frag buffers                @ 218365952
// ---------------------------------------------------------------------------

typedef __attribute__((ext_vector_type(8))) short bf16x8;
typedef __attribute__((ext_vector_type(4))) short s16x4;
typedef __attribute__((ext_vector_type(4))) float f32x4;

#define MFMA16(a,b,c) __builtin_amdgcn_mfma_f32_16x16x32_bf16(a,b,c,0,0,0)

__device__ __forceinline__ ushort f2bf(float f){
  uint u = __float_as_uint(f);
  return (ushort)((u + 0x7fffu + ((u >> 16) & 1u)) >> 16);
}
__device__ __forceinline__ float bf2f(ushort h){
  return __uint_as_float(((uint)h) << 16);
}
__device__ __forceinline__ float frelu(float v){ return v > 0.f ? v : 0.f; }

__global__ void k_zero1(float* p){ *p = 0.f; }

// ---------------- weight prep kernels --------------------------------------
// W2F[khw16][icb4][ocT16][lane64][j8], hi+lo
__global__ __launch_bounds__(256) void k_w2f(const float* __restrict__ w,
                                             ushort* __restrict__ fh, ushort* __restrict__ fl){
  int i = blockIdx.x*256 + threadIdx.x;            // 524288
  int j = i & 7, l = (i >> 3) & 63, rest = i >> 9;
  int ocT = rest & 15, icb = (rest >> 4) & 3, khw = rest >> 6;
  int oc = ocT*16 + (l & 15);
  int ic = icb*32 + (l >> 4)*8 + j;
  float v = w[(oc*128 + ic)*16 + khw];
  ushort h = f2bf(v);
  fh[i] = h; fl[i] = f2bf(v - bf2f(h));
}
// W3F[khw9][icb8][ocT4][...], hi+lo
__global__ __launch_bounds__(256) void k_w3f(const float* __restrict__ w,
                                             ushort* __restrict__ fh, ushort* __restrict__ fl){
  int i = blockIdx.x*256 + threadIdx.x;            // 147456
  if (i >= 147456) return;
  int j = i & 7, l = (i >> 3) & 63, rest = i >> 9;
  int ocT = rest & 3, r2 = rest >> 2;
  int icb = r2 & 7, khw = r2 >> 3;
  int oc = ocT*16 + (l & 15);
  int ic = icb*32 + (l >> 4)*8 + j;
  float v = w[(oc*256 + ic)*9 + khw];
  ushort h = f2bf(v);
  fh[i] = h; fl[i] = f2bf(v - bf2f(h));
}
// W5F[khw9][icb2][ocT16][...], single
__global__ __launch_bounds__(256) void k_w5f(const float* __restrict__ w,
                                             ushort* __restrict__ f){
  int i = blockIdx.x*256 + threadIdx.x;            // 147456
  if (i >= 147456) return;
  int j = i & 7, l = (i >> 3) & 63, rest = i >> 9;
  int ocT = rest & 15, r2 = rest >> 4;
  int icb = r2 & 1, khw = r2 >> 1;
  int oc = ocT*16 + (l & 15);
  int ic = icb*32 + (l >> 4)*8 + j;
  f[i] = f2bf(w[(oc*64 + ic)*9 + khw]);
}
// W6F[par4][dhw4][icb8][ocT8][...], single
__global__ __launch_bounds__(256) void k_w6f(const float* __restrict__ w,
                                             ushort* __restrict__ f){
  int i = blockIdx.x*256 + threadIdx.x;            // 524288
  int j = i & 7, l = (i >> 3) & 63, rest = i >> 9;
  int ocT = rest & 7, icb = (rest >> 3) & 7, dhw = (rest >> 6) & 3, par = rest >> 8;
  int po = par >> 1, pw = par & 1;
  int kh = po + 2*(dhw >> 1), kw = pw + 2*(dhw & 1);
  int oc = ocT*16 + (l & 15);
  int ic = icb*32 + (l >> 4)*8 + j;
  f[i] = f2bf(w[(oc*256 + ic)*16 + kh*4 + kw]);
}
// W7F[par4][icb4][dhw4][1 ocT pad16][...], single
__global__ __launch_bounds__(256) void k_w7f(const float* __restrict__ w,
                                             ushort* __restrict__ f){
  int i = blockIdx.x*256 + threadIdx.x;            // 32768
  if (i >= 32768) return;
  int j = i & 7, l = (i >> 3) & 63, rest = i >> 9;
  int dhw = rest & 3, icb = (rest >> 2) & 3, par = (rest >> 4) & 3;
  int po = par >> 1, pw = par & 1;
  int kh = po + 2*(dhw >> 1), kw = pw + 2*(dhw & 1);
  int ocr = l & 15;
  int ic = icb*32 + (l >> 4)*8 + j;
  float v = (ocr < 3) ? w[(ocr*128 + ic)*16 + kh*4 + kw] : 0.f;
  f[i] = f2bf(v);
}
// CBF[codeT32][kst2][...], hi+lo
__global__ __launch_bounds__(256) void k_cbf(const float* __restrict__ cb,
                                             ushort* __restrict__ fh, ushort* __restrict__ fl){
  int i = blockIdx.x*256 + threadIdx.x;            // 32768
  if (i >= 32768) return;
  int j = i & 7, l = (i >> 3) & 63, rest = i >> 9;
  int kst = rest & 1, cT = rest >> 1;
  int code = cT*16 + (l & 15);
  int d = kst*32 + (l >> 4)*8 + j;
  float v = cb[code*64 + d];
  ushort h = f2bf(v);
  fh[i] = h; fl[i] = f2bf(v - bf2f(h));
}
// code norms
__global__ __launch_bounds__(256) void k_cn(const float* __restrict__ cb,
                                            float* __restrict__ cn){
  int c = blockIdx.x*256 + threadIdx.x;
  if (c >= 512) return;
  const float* p = cb + c*64;
  float s = 0.f;
  #pragma unroll
  for (int d = 0; d < 64; d += 4){
    float4 u = *(const float4*)(p + d);
    s = fmaf(u.x,u.x, fmaf(u.y,u.y, fmaf(u.z,u.z, fmaf(u.w,u.w, s))));
  }
  cn[c] = s;
}

// ---- conv1 EXACT fp32 (LDS-staged): x -> H1 hi/lo bf16 NHWC, k4 s2 p1 -----
// Bit-identical fmaf chain to r3/r6. Block (b,oh); LDS holds the 12 input
// rows (3c x 4kh) x 258 cols; compute reads are wave-uniform broadcasts.
__global__ __launch_bounds__(256,4) void k_conv1(const float* __restrict__ x,
    const float* __restrict__ w, const float* __restrict__ bias,
    ushort* __restrict__ yh, ushort* __restrict__ yl){
  __shared__ float Xs[12*260];                     // [c*4+kh][260], col = iw+1
  int t = threadIdx.x;
  int bid = blockIdx.x;
  int oh = bid & 127, b = bid >> 7;

  for (int e = t; e < 12*258; e += 256){
    int rowid = e / 258, col = e - rowid*258;
    int c = rowid >> 2, kh = rowid & 3;
    int ih = oh*2 - 1 + kh;
    int iw = col - 1;
    float v = 0.f;
    if ((unsigned)ih < 256u && (unsigned)iw < 256u)
      v = x[(b*3 + c)*65536 + ih*256 + iw];
    Xs[rowid*260 + col] = v;
  }

  int oc = t & 127, half = t >> 7;
  float wv[48];
  const float* wp = w + oc*48;
  #pragma unroll
  for (int i = 0; i < 48; i += 4){
    float4 u = *(const float4*)(wp + i);
    wv[i] = u.x; wv[i+1] = u.y; wv[i+2] = u.z; wv[i+3] = u.w;
  }
  float bv = bias[oc];
  __syncthreads();

  for (int ch = 0; ch < 8; ch++){
    int ow0 = half*64 + ch*8;
    float acc[8];
    #pragma unroll
    for (int i = 0; i < 8; i++) acc[i] = bv;
    #pragma unroll
    for (int c = 0; c < 3; c++){
      #pragma unroll
      for (int kh = 0; kh < 4; kh++){
        const float* lp = Xs + (c*4 + kh)*260 + ow0*2;   // col(iw=ow0*2-1) = ow0*2
        float xr[20];
        #pragma unroll
        for (int q = 0; q < 5; q++){
          float4 u = *(const float4*)(lp + q*4);
          xr[q*4] = u.x; xr[q*4+1] = u.y; xr[q*4+2] = u.z; xr[q*4+3] = u.w;
        }
        #pragma unroll
        for (int i = 0; i < 8; i++){
          #pragma unroll
          for (int kw = 0; kw < 4; kw++)
            acc[i] = fmaf(xr[2*i + kw], wv[c*16 + kh*4 + kw], acc[i]);
        }
      }
    }
    #pragma unroll
    for (int i = 0; i < 8; i++){
      float v = frelu(acc[i]);
      ushort h = f2bf(v);
      ushort l = f2bf(v - bf2f(h));
      int off = ((b*128 + oh)*128 + (ow0 + i))*128 + oc;
      yh[off] = h; yl[off] = l;
    }
  }
}

// ---- conv2: H1 hi/lo -> H2 hi/lo, k4 s2 p1, relu, split-3 MFMA ------------
// tile 16x8 out, all 256 oc; wave = 64 oc x 128 pos.
// LDS parity-deinterleaved: granule((c&1)*4+gq, r, c>>1), dims [8][34][9].
// Read col = (li&7) stride-1 -> conflict-free (<=2-way).
__global__ __launch_bounds__(256,2) void k_conv2(const ushort* __restrict__ xh,
    const ushort* __restrict__ xl,
    const ushort* __restrict__ wfh, const ushort* __restrict__ wfl,
    const float* __restrict__ bias,
    ushort* __restrict__ yh, ushort* __restrict__ yl){
  __shared__ ushort Xs[2*2448*8];                  // hi plane, lo plane (78336B)
  int t = threadIdx.x;
  int li = t & 15, g4 = (t >> 4) & 3, lane = t & 63, wq = t >> 6;
  int bid = blockIdx.x;
  int tile = bid & 31, b = bid >> 5;
  int OH0 = (tile >> 3)*16, OW0 = (tile & 7)*8;
  int ih0 = OH0*2 - 1, iw0 = OW0*2 - 1;
  f32x4 acc[4][8];
  #pragma unroll
  for (int m = 0; m < 4; m++)
    #pragma unroll
    for (int n = 0; n < 8; n++) acc[m][n] = (f32x4){0.f,0.f,0.f,0.f};

  int rb = (li >> 3)*2, c8 = li & 7;

  for (int icb = 0; icb < 4; icb++){
    __syncthreads();
    for (int e = t; e < 2448; e += 256){
      int gq = e / 612, cell = e - gq*612;
      int r = cell / 18, c = cell - r*18;
      int ih = ih0 + r, iw = iw0 + c;
      bf16x8 vh = {0,0,0,0,0,0,0,0}, vl = {0,0,0,0,0,0,0,0};
      if ((unsigned)ih < 128u && (unsigned)iw < 128u){
        int off = ((b*128 + ih)*128 + iw)*128 + icb*32 + gq*8;
        vh = *(const bf16x8*)(xh + off);
        vl = *(const bf16x8*)(xl + off);
      }
      int g2 = (((c & 1)*4 + gq)*34 + r)*9 + (c >> 1);
      *(bf16x8*)(Xs + g2*8) = vh;
      *(bf16x8*)(Xs + (2448 + g2)*8) = vl;
    }
    __syncthreads();
    for (int khw = 0; khw < 16; khw++){
      int kh = khw >> 2, kw = khw & 3;
      const ushort* aph = wfh + ((khw*4 + icb)*16)*512 + lane*8;
      const ushort* apl = wfl + ((khw*4 + icb)*16)*512 + lane*8;
      bf16x8 Ah[4], Al[4];
      #pragma unroll
      for (int m = 0; m < 4; m++){
        Ah[m] = *(const bf16x8*)(aph + (wq*4 + m)*512);
        Al[m] = *(const bf16x8*)(apl + (wq*4 + m)*512);
      }
      int base0 = (((kw & 1)*4 + g4)*34 + rb + kh)*9 + c8 + (kw >> 1);
      #pragma unroll
      for (int n = 0; n < 8; n++){
        int gran = base0 + n*36;
        bf16x8 Bh = *(const bf16x8*)(Xs + gran*8);
        bf16x8 Bl = *(const bf16x8*)(Xs + (2448 + gran)*8);
        #pragma unroll
        for (int m = 0; m < 4; m++){
          acc[m][n] = MFMA16(Ah[m], Bh, acc[m][n]);
          acc[m][n] = MFMA16(Al[m], Bh, acc[m][n]);
          acc[m][n] = MFMA16(Ah[m], Bl, acc[m][n]);
        }
      }
    }
  }
  #pragma unroll
  for (int m = 0; m < 4; m++){
    f32x4 bv = *(const f32x4*)(bias + wq*64 + m*16 + g4*4);
    #pragma unroll
    for (int n = 0; n < 8; n++){
      int oh = OH0 + 2*n + (li >> 3);
      int ow = OW0 + (li & 7);
      int off = ((b*64 + oh)*64 + ow)*256 + wq*64 + m*16 + g4*4;
      s16x4 h4, l4;
      #pragma unroll
      for (int r = 0; r < 4; r++){
        float v = frelu(acc[m][n][r] + bv[r]);
        ushort h = f2bf(v);
        h4[r] = (short)h;
        l4[r] = (short)f2bf(v - bf2f(h));
      }
      *(s16x4*)(yh + off) = h4;
      *(s16x4*)(yl + off) = l4;
    }
  }
}

// ---- conv3: H2 hi/lo -> ZF f32 [65536][64], k3 s1 p1, split-3 MFMA --------
// tile 16x32, 64 oc (all waves); wave = 64 oc x 128 pos.  R=18 C=34.
__global__ __launch_bounds__(256,2) void k_conv3(const ushort* __restrict__ xh,
    const ushort* __restrict__ xl,
    const ushort* __restrict__ wfh, const ushort* __restrict__ wfl,
    const float* __restrict__ bias, float* __restrict__ zf){
  __shared__ ushort Xs[2*2448*8];
  int t = threadIdx.x;
  int li = t & 15, g4 = (t >> 4) & 3, lane = t & 63, wq = t >> 6;
  int bid = blockIdx.x;
  int tile = bid & 7, b = bid >> 3;
  int OH0 = (tile >> 1)*16, OW0 = (tile & 1)*32;
  f32x4 acc[4][8];
  #pragma unroll
  for (int m = 0; m < 4; m++)
    #pragma unroll
    for (int n = 0; n < 8; n++) acc[m][n] = (f32x4){0.f,0.f,0.f,0.f};

  for (int icb = 0; icb < 8; icb++){
    __syncthreads();
    for (int e = t; e < 2448; e += 256){
      int gq = e / 612, cell = e - gq*612;
      int r = cell / 34, c = cell - r*34;
      int ih = OH0 - 1 + r, iw = OW0 - 1 + c;
      bf16x8 vh = {0,0,0,0,0,0,0,0}, vl = {0,0,0,0,0,0,0,0};
      if ((unsigned)ih < 64u && (unsigned)iw < 64u){
        int off = ((b*64 + ih)*64 + iw)*256 + icb*32 + gq*8;
        vh = *(const bf16x8*)(xh + off);
        vl = *(const bf16x8*)(xl + off);
      }
      *(bf16x8*)(Xs + e*8) = vh;
      *(bf16x8*)(Xs + (2448 + e)*8) = vl;
    }
    __syncthreads();
    #pragma unroll
    for (int kh = 0; kh < 3; kh++){
      #pragma unroll
      for (int kw = 0; kw < 3; kw++){
        int khw = kh*3 + kw;
        const ushort* aph = wfh + ((khw*8 + icb)*4)*512 + lane*8;
        const ushort* apl = wfl + ((khw*8 + icb)*4)*512 + lane*8;
        bf16x8 Ah[4], Al[4];
        #pragma unroll
        for (int m = 0; m < 4; m++){
          Ah[m] = *(const bf16x8*)(aph + m*512);
          Al[m] = *(const bf16x8*)(apl + m*512);
        }
        #pragma unroll
        for (int n = 0; n < 8; n++){
          int gran = g4*612 + (wq*4 + (n >> 1) + kh)*34 + (n & 1)*16 + li + kw;
          bf16x8 Bh = *(const bf16x8*)(Xs + gran*8);
          bf16x8 Bl = *(const bf16x8*)(Xs + (2448 + gran)*8);
          #pragma unroll
          for (int m = 0; m < 4; m++){
            acc[m][n] = MFMA16(Ah[m], Bh, acc[m][n]);
            acc[m][n] = MFMA16(Al[m], Bh, acc[m][n]);
            acc[m][n] = MFMA16(Ah[m], Bl, acc[m][n]);
          }
        }
      }
    }
  }
  #pragma unroll
  for (int m = 0; m < 4; m++){
    f32x4 bv = *(const f32x4*)(bias + m*16 + g4*4);
    #pragma unroll
    for (int n = 0; n < 8; n++){
      int oh = OH0 + wq*4 + (n >> 1);
      int ow = OW0 + (n & 1)*16 + li;
      int nIdx = (b*64 + oh)*64 + ow;
      f32x4 v = acc[m][n] + bv;
      *(f32x4*)(zf + nIdx*64 + m*16 + g4*4) = v;
    }
  }
}

// ---- vqdist: argmin over 512 codes via split-3 MFMA -----------------------
__global__ __launch_bounds__(256) void k_vqdist(const float* __restrict__ zf,
    const ushort* __restrict__ cfh, const ushort* __restrict__ cfl,
    const float* __restrict__ cn, int* __restrict__ idxOut){
  int t = threadIdx.x;
  int lane = t & 63, wq = t >> 6;
  int li = lane & 15, g = lane >> 4;
  int rowBase = blockIdx.x*64 + wq*16;
  bf16x8 Bh[2], Bl[2];
  const float* zp = zf + (rowBase + li)*64 + g*8;
  #pragma unroll
  for (int kst = 0; kst < 2; kst++){
    float4 u0 = *(const float4*)(zp + kst*32);
    float4 u1 = *(const float4*)(zp + kst*32 + 4);
    float v[8] = {u0.x,u0.y,u0.z,u0.w,u1.x,u1.y,u1.z,u1.w};
    #pragma unroll
    for (int j = 0; j < 8; j++){
      ushort h = f2bf(v[j]);
      Bh[kst][j] = (short)h;
      Bl[kst][j] = (short)f2bf(v[j] - bf2f(h));
    }
  }
  float best = 3.4e38f; int bi = 0;
  for (int ch = 0; ch < 8; ch++){
    f32x4 acc[4];
    #pragma unroll
    for (int m = 0; m < 4; m++) acc[m] = (f32x4){0.f,0.f,0.f,0.f};
    #pragma unroll
    for (int kst = 0; kst < 2; kst++){
      #pragma unroll
      for (int m = 0; m < 4; m++){
        int cT = ch*4 + m;
        bf16x8 Ah = *(const bf16x8*)(cfh + (cT*2 + kst)*512 + lane*8);
        bf16x8 Al = *(const bf16x8*)(cfl + (cT*2 + kst)*512 + lane*8);
        acc[m] = MFMA16(Ah, Bh[kst], acc[m]);
        acc[m] = MFMA16(Al, Bh[kst], acc[m]);
        acc[m] = MFMA16(Ah, Bl[kst], acc[m]);
      }
    }
    #pragma unroll
    for (int m = 0; m < 4; m++){
      #pragma unroll
      for (int r = 0; r < 4; r++){
        int code = (ch*4 + m)*16 + g*4 + r;
        float d2 = cn[code] - 2.f*acc[m][r];
        if (d2 < best){ best = d2; bi = code; }
      }
    }
  }
  #pragma unroll
  for (int off = 32; off >= 16; off >>= 1){
    float ob = __shfl_down(best, off);
    int oi = __shfl_down(bi, off);
    if (ob < best || (ob == best && oi < bi)){ best = ob; bi = oi; }
  }
  if (lane < 16) idxOut[rowBase + li] = bi;
}

// ---- vqgather: q write (bf16) + vq loss -----------------------------------
__global__ __launch_bounds__(256) void k_vqgather(const float* __restrict__ zf,
    const float* __restrict__ cb, const int* __restrict__ idx,
    ushort* __restrict__ qx, float* __restrict__ lossp){
  int n = blockIdx.x*256 + threadIdx.x;
  int code = idx[n];
  const float* cp = cb + code*64;
  const float* zp = zf + n*64;
  float ls = 0.f;
  #pragma unroll
  for (int d = 0; d < 64; d += 4){
    float4 qv = *(const float4*)(cp + d);
    float4 zv = *(const float4*)(zp + d);
    float d0 = qv.x - zv.x, d1 = qv.y - zv.y, d2 = qv.z - zv.z, d3 = qv.w - zv.w;
    ls = fmaf(d0,d0, fmaf(d1,d1, fmaf(d2,d2, fmaf(d3,d3, ls))));
    s16x4 q4;
    q4[0] = (short)f2bf(qv.x); q4[1] = (short)f2bf(qv.y);
    q4[2] = (short)f2bf(qv.z); q4[3] = (short)f2bf(qv.w);
    *(s16x4*)(qx + n*64 + d) = q4;
  }
  #pragma unroll
  for (int off = 32; off > 0; off >>= 1) ls += __shfl_down(ls, off);
  if ((threadIdx.x & 63) == 0) atomicAdd(lossp, ls * (1.25f/4194304.f));
}

// ---- dec1: QX -> D1, k3 s1 p1, relu, single MFMA --------------------------
// tile 16x8, 256 oc; wave = 128 oc x 64 pos.  R=18 C=10.
__global__ __launch_bounds__(256,2) void k_dec1(const ushort* __restrict__ xq,
    const ushort* __restrict__ wf, const float* __restrict__ bias,
    ushort* __restrict__ y){
  __shared__ ushort Xs[720*8];                     // 11520B
  int t = threadIdx.x;
  int li = t & 15, g4 = (t >> 4) & 3, lane = t & 63, wq = t >> 6;
  int och = wq >> 1, ph = wq & 1;
  int bid = blockIdx.x;
  int tile = bid & 31, b = bid >> 5;
  int OH0 = (tile >> 3)*16, OW0 = (tile & 7)*8;
  f32x4 acc[8][4];
  #pragma unroll
  for (int m = 0; m < 8; m++)
    #pragma unroll
    for (int n = 0; n < 4; n++) acc[m][n] = (f32x4){0.f,0.f,0.f,0.f};

  for (int icb = 0; icb < 2; icb++){
    __syncthreads();
    for (int e = t; e < 720; e += 256){
      int gq = e / 180, cell = e - gq*180;
      int r = cell / 10, c = cell - r*10;
      int ih = OH0 - 1 + r, iw = OW0 - 1 + c;
      bf16x8 v = {0,0,0,0,0,0,0,0};
      if ((unsigned)ih < 64u && (unsigned)iw < 64u)
        v = *(const bf16x8*)(xq + ((b*64 + ih)*64 + iw)*64 + icb*32 + gq*8);
      *(bf16x8*)(Xs + e*8) = v;
    }
    __syncthreads();
    #pragma unroll
    for (int kh = 0; kh < 3; kh++){
      #pragma unroll
      for (int kw = 0; kw < 3; kw++){
        int khw = kh*3 + kw;
        const ushort* ap = wf + ((khw*2 + icb)*16)*512 + lane*8;
        bf16x8 A[8];
        #pragma unroll
        for (int m = 0; m < 8; m++)
          A[m] = *(const bf16x8*)(ap + (och*8 + m)*512);
        #pragma unroll
        for (int nn = 0; nn < 4; nn++){
          int nT = ph*4 + nn;
          int gran = g4*180 + (nT*2 + (li >> 3) + kh)*10 + (li & 7) + kw;
          bf16x8 B = *(const bf16x8*)(Xs + gran*8);
          #pragma unroll
          for (int m = 0; m < 8; m++)
            acc[m][nn] = MFMA16(A[m], B, acc[m][nn]);
        }
      }
    }
  }
  #pragma unroll
  for (int m = 0; m < 8; m++){
    int oc = och*128 + m*16 + g4*4;
    f32x4 bv = *(const f32x4*)(bias + oc);
    #pragma unroll
    for (int nn = 0; nn < 4; nn++){
      int nT = ph*4 + nn;
      int oh = OH0 + nT*2 + (li >> 3);
      int ow = OW0 + (li & 7);
      s16x4 h4;
      #pragma unroll
      for (int r = 0; r < 4; r++)
        h4[r] = (short)f2bf(frelu(acc[m][nn][r] + bv[r]));
      *(s16x4*)(y + ((b*64 + oh)*64 + ow)*256 + oc) = h4;
    }
  }
}

// ---- deconv2: D1 -> D2, transposed k4 s2 p1, relu, single MFMA ------------
// out tile 16x16; wave = parity class, 128 oc x 64 pos.  R=10 C=10.
__global__ __launch_bounds__(256,2) void k_deconv2(const ushort* __restrict__ xq,
    const ushort* __restrict__ wf, const float* __restrict__ bias,
    ushort* __restrict__ y){
  __shared__ ushort Xs[400*8];                     // 6400B
  int t = threadIdx.x;
  int li = t & 15, g4 = (t >> 4) & 3, lane = t & 63, wq = t >> 6;
  int po = wq >> 1, pw = wq & 1;
  int bid = blockIdx.x;
  int tile = bid & 63, b = bid >> 6;
  int Y0 = (tile >> 3)*8, X0 = (tile & 7)*8;
  f32x4 acc[8][4];
  #pragma unroll
  for (int m = 0; m < 8; m++)
    #pragma unroll
    for (int n = 0; n < 4; n++) acc[m][n] = (f32x4){0.f,0.f,0.f,0.f};

  for (int icb = 0; icb < 8; icb++){
    __syncthreads();
    for (int e = t; e < 400; e += 256){
      int gq = e / 100, cell = e - gq*100;
      int r = cell / 10, c = cell - r*10;
      int ih = Y0 - 1 + r, iw = X0 - 1 + c;
      bf16x8 v = {0,0,0,0,0,0,0,0};
      if ((unsigned)ih < 64u && (unsigned)iw < 64u)
        v = *(const bf16x8*)(xq + ((b*64 + ih)*64 + iw)*256 + icb*32 + gq*8);
      *(bf16x8*)(Xs + e*8) = v;
    }
    __syncthreads();
    #pragma unroll
    for (int dhw = 0; dhw < 4; dhw++){
      int dh = dhw >> 1, dw = dhw & 1;
      const ushort* ap = wf + (((wq*4 + dhw)*8 + icb)*8)*512 + lane*8;
      bf16x8 A[8];
      #pragma unroll
      for (int m = 0; m < 8; m++)
        A[m] = *(const bf16x8*)(ap + m*512);
      #pragma unroll
      for (int nn = 0; nn < 4; nn++){
        int yy = nn*2 + (li >> 3), xx = li & 7;
        int gran = g4*100 + (yy + dh + po)*10 + xx + dw + pw;
        bf16x8 B = *(const bf16x8*)(Xs + gran*8);
        #pragma unroll
        for (int m = 0; m < 8; m++)
          acc[m][nn] = MFMA16(A[m], B, acc[m][nn]);
      }
    }
  }
  #pragma unroll
  for (int m = 0; m < 8; m++){
    int oc = m*16 + g4*4;
    f32x4 bv = *(const f32x4*)(bias + oc);
    #pragma unroll
    for (int nn = 0; nn < 4; nn++){
      int yy = nn*2 + (li >> 3), xx = li & 7;
      int oh = 2*(Y0 + yy) + po, ow = 2*(X0 + xx) + pw;
      s16x4 h4;
      #pragma unroll
      for (int r = 0; r < 4; r++)
        h4[r] = (short)f2bf(frelu(acc[m][nn][r] + bv[r]));
      *(s16x4*)(y + ((b*128 + oh)*128 + ow)*128 + oc) = h4;
    }
  }
}

// ---- deconv3: D2 -> out f32 NCHW, transposed k4 s2 p1, single MFMA (M pad 16)
// out tile 32x32; wave = parity class, 3 oc x 256 pos.  R=18 C=18.
__global__ __launch_bounds__(256,2) void k_deconv3(const ushort* __restrict__ xq,
    const ushort* __restrict__ wf, const float* __restrict__ bias,
    float* __restrict__ out){
  __shared__ ushort Xs[1296*8];                    // 20736B
  int t = threadIdx.x;
  int li = t & 15, g4 = (t >> 4) & 3, lane = t & 63, wq = t >> 6;
  int po = wq >> 1, pw = wq & 1;
  int bid = blockIdx.x;
  int tile = bid & 63, b = bid >> 6;
  int Y0 = (tile >> 3)*16, X0 = (tile & 7)*16;
  f32x4 acc[16];
  #pragma unroll
  for (int n = 0; n < 16; n++) acc[n] = (f32x4){0.f,0.f,0.f,0.f};

  for (int icb = 0; icb < 4; icb++){
    __syncthreads();
    for (int e = t; e < 1296; e += 256){
      int gq = e / 324, cell = e - gq*324;
      int r = cell / 18, c = cell - r*18;
      int ih = Y0 - 1 + r, iw = X0 - 1 + c;
      bf16x8 v = {0,0,0,0,0,0,0,0};
      if ((unsigned)ih < 128u && (unsigned)iw < 128u)
        v = *(const bf16x8*)(xq + ((b*128 + ih)*128 + iw)*128 + icb*32 + gq*8);
      *(bf16x8*)(Xs + e*8) = v;
    }
    __syncthreads();
    #pragma unroll
    for (int dhw = 0; dhw < 4; dhw++){
      int dh = dhw >> 1, dw = dhw & 1;
      bf16x8 A = *(const bf16x8*)(wf + ((wq*4 + icb)*4 + dhw)*512 + lane*8);
      #pragma unroll
      for (int n = 0; n < 16; n++){
        int gran = g4*324 + (n + dh + po)*18 + li + dw + pw;
        bf16x8 B = *(const bf16x8*)(Xs + gran*8);
        acc[n] = MFMA16(A, B, acc[n]);
      }
    }
  }
  if (g4 == 0){
    float b0 = bias[0], b1 = bias[1], b2 = bias[2];
    #pragma unroll
    for (int n = 0; n < 16; n++){
      int oh = 2*(Y0 + n) + po, ow = 2*(X0 + li) + pw;
      int base = b*196608 + oh*256 + ow;
      out[base]           = acc[n][0] + b0;
      out[base + 65536]   = acc[n][1] + b1;
      out[base + 131072]  = acc[n][2] + b2;
    }
  }
}

// ---------------------------------------------------------------------------
extern "C" void kernel_launch(void* const* d_in, const int* in_sizes, int n_in,
                              void* d_out, int out_size, void* d_ws, size_t ws_size,
                              hipStream_t stream){
  (void)in_sizes; (void)n_in; (void)out_size; (void)ws_size;
  const float* x   = (const float*)d_in[0];
  const float* ew1 = (const float*)d_in[1];
  const float* eb1 = (const float*)d_in[2];
  const float* ew2 = (const float*)d_in[3];
  const float* eb2 = (const float*)d_in[4];
  const float* ew3 = (const float*)d_in[5];
  const float* eb3 = (const float*)d_in[6];
  const float* cb  = (const float*)d_in[7];
  const float* dw1 = (const float*)d_in[8];
  const float* db1 = (const float*)d_in[9];
  const float* dw2 = (const float*)d_in[10];
  const float* db2 = (const float*)d_in[11];
  const float* dw3 = (const float*)d_in[12];
  const float* db3 = (const float*)d_in[13];
  float* out = (float*)d_out;
  char* w = (char*)d_ws;

  ushort* H1H  = (ushort*)(w + 0);
  ushort* H1L  = (ushort*)(w + 67108864);
  ushort* D1   = (ushort*)(w + 0);           // reuse (after conv2)
  ushort* H2H  = (ushort*)(w + 134217728);
  ushort* H2L  = (ushort*)(w + 167772160);
  ushort* QX   = (ushort*)(w + 134217728);   // reuse (after conv3)
  ushort* D2   = (ushort*)(w + 150994944);
  float*  ZF   = (float*)(w + 201326592);
  int*    IDX  = (int*)(w + 218103808);
  ushort* W2FH = (ushort*)(w + 218365952);
  ushort* W2FL = (ushort*)(w + 219414528);
  ushort* W3FH = (ushort*)(w + 220463104);
  ushort* W3FL = (ushort*)(w + 220758016);
  ushort* W5F  = (ushort*)(w + 221052928);
  ushort* W6F  = (ushort*)(w + 221347840);
  ushort* W7F  = (ushort*)(w + 222396416);
  ushort* CBFH = (ushort*)(w + 222461952);
  ushort* CBFL = (ushort*)(w + 222527488);
  float*  CN   = (float*)(w + 222593024);

  k_w2f<<<2048, 256, 0, stream>>>(ew2, W2FH, W2FL);
  k_w3f<<<576,  256, 0, stream>>>(ew3, W3FH, W3FL);
  k_w5f<<<576,  256, 0, stream>>>(dw1, W5F);
  k_w6f<<<2048, 256, 0, stream>>>(dw2, W6F);
  k_w7f<<<128,  256, 0, stream>>>(dw3, W7F);
  k_cbf<<<128,  256, 0, stream>>>(cb, CBFH, CBFL);
  k_cn<<<2,     256, 0, stream>>>(cb, CN);
  k_zero1<<<1, 1, 0, stream>>>(out + 3145728);

  k_conv1<<<2048, 256, 0, stream>>>(x, ew1, eb1, H1H, H1L);
  k_conv2<<<512,  256, 0, stream>>>(H1H, H1L, W2FH, W2FL, eb2, H2H, H2L);
  k_conv3<<<128,  256, 0, stream>>>(H2H, H2L, W3FH, W3FL, eb3, ZF);
  k_vqdist<<<1024, 256, 0, stream>>>(ZF, CBFH, CBFL, CN, IDX);
  k_vqgather<<<256, 256, 0, stream>>>(ZF, cb, IDX, QX, out + 3145728);
  k_dec1<<<512,   256, 0, stream>>>(QX, W5F, db1, D1);
  k_deconv2<<<1024, 256, 0, stream>>>(D1, W6F, db2, D2);
  k_deconv3<<<1024, 256, 0, stream>>>(D2, W7F, db3, out);
}

// Round 10
// 677.726 us; speedup vs baseline: 6.5319x; 1.4400x over previous
//
#include <hip/hip_runtime.h>

// ---------------------------------------------------------------------------
// VQ-VAE forward (r9): conv2/conv3 re-tiled for occupancy.
//  - conv3: 8x16 tile, grid 512, LDS 23KB, 4 blocks/CU (was 16x32/128/78KB).
//  - conv2: 8x8 tile, grid 1024, LDS 41.5KB, 3 blocks/CU (was 16x8/512/78KB).
//  Accumulation order per output unchanged -> bit-identical encoder/argmins.
// conv1: exact fp32 LDS-staged. Encoder+VQ: split-bf16 3-product MFMA.
// Decoder: single bf16 MFMA.
//
// MFMA 16x16x32 bf16 fragments (gfx950, learn_hip m89-verified):
//   A[m][k]: lane l, j -> A[l&15][(l>>4)*8 + j]
//   B[k][n]: lane l, j -> B[(l>>4)*8 + j][l&15]
//   D[m][n]: lane l, r -> D[(l>>4)*4 + r][l&15]
//
// Workspace (byte offsets):
//   H1H bf16 NHWC [16][128][128][128]  @ 0          (67,108,864)
//   H1L bf16                           @ 67108864   (67,108,864)
//   D1  bf16 NHWC [16][64][64][256]    @ 0          (reuse after conv2)
//   H2H bf16 NHWC [16][64][64][256]    @ 134217728  (33,554,432)
//   H2L bf16                           @ 167772160  (33,554,432)
//   QX  bf16 NHWC [16][64][64][64]     @ 134217728  (reuse after conv3)
//   D2  bf16 NHWC [16][128][128][128]  @ 150994944  (33,554,432)
//   ZF  f32 [65536][64]                @ 201326592  (16,777,216)
//   IDX int32 [65536]                  @ 218103808  (262,144)
//   weight frag buffers                @ 218365952
// ---------------------------------------------------------------------------

typedef __attribute__((ext_vector_type(8))) short bf16x8;
typedef __attribute__((ext_vector_type(4))) short s16x4;
typedef __attribute__((ext_vector_type(4))) float f32x4;

#define MFMA16(a,b,c) __builtin_amdgcn_mfma_f32_16x16x32_bf16(a,b,c,0,0,0)

__device__ __forceinline__ ushort f2bf(float f){
  uint u = __float_as_uint(f);
  return (ushort)((u + 0x7fffu + ((u >> 16) & 1u)) >> 16);
}
__device__ __forceinline__ float bf2f(ushort h){
  return __uint_as_float(((uint)h) << 16);
}
__device__ __forceinline__ float frelu(float v){ return v > 0.f ? v : 0.f; }

__global__ void k_zero1(float* p){ *p = 0.f; }

// ---------------- weight prep kernels --------------------------------------
// W2F[khw16][icb4][ocT16][lane64][j8], hi+lo
__global__ __launch_bounds__(256) void k_w2f(const float* __restrict__ w,
                                             ushort* __restrict__ fh, ushort* __restrict__ fl){
  int i = blockIdx.x*256 + threadIdx.x;            // 524288
  int j = i & 7, l = (i >> 3) & 63, rest = i >> 9;
  int ocT = rest & 15, icb = (rest >> 4) & 3, khw = rest >> 6;
  int oc = ocT*16 + (l & 15);
  int ic = icb*32 + (l >> 4)*8 + j;
  float v = w[(oc*128 + ic)*16 + khw];
  ushort h = f2bf(v);
  fh[i] = h; fl[i] = f2bf(v - bf2f(h));
}
// W3F[khw9][icb8][ocT4][...], hi+lo
__global__ __launch_bounds__(256) void k_w3f(const float* __restrict__ w,
                                             ushort* __restrict__ fh, ushort* __restrict__ fl){
  int i = blockIdx.x*256 + threadIdx.x;            // 147456
  if (i >= 147456) return;
  int j = i & 7, l = (i >> 3) & 63, rest = i >> 9;
  int ocT = rest & 3, r2 = rest >> 2;
  int icb = r2 & 7, khw = r2 >> 3;
  int oc = ocT*16 + (l & 15);
  int ic = icb*32 + (l >> 4)*8 + j;
  float v = w[(oc*256 + ic)*9 + khw];
  ushort h = f2bf(v);
  fh[i] = h; fl[i] = f2bf(v - bf2f(h));
}
// W5F[khw9][icb2][ocT16][...], single
__global__ __launch_bounds__(256) void k_w5f(const float* __restrict__ w,
                                             ushort* __restrict__ f){
  int i = blockIdx.x*256 + threadIdx.x;            // 147456
  if (i >= 147456) return;
  int j = i & 7, l = (i >> 3) & 63, rest = i >> 9;
  int ocT = rest & 15, r2 = rest >> 4;
  int icb = r2 & 1, khw = r2 >> 1;
  int oc = ocT*16 + (l & 15);
  int ic = icb*32 + (l >> 4)*8 + j;
  f[i] = f2bf(w[(oc*64 + ic)*9 + khw]);
}
// W6F[par4][dhw4][icb8][ocT8][...], single
__global__ __launch_bounds__(256) void k_w6f(const float* __restrict__ w,
                                             ushort* __restrict__ f){
  int i = blockIdx.x*256 + threadIdx.x;            // 524288
  int j = i & 7, l = (i >> 3) & 63, rest = i >> 9;
  int ocT = rest & 7, icb = (rest >> 3) & 7, dhw = (rest >> 6) & 3, par = rest >> 8;
  int po = par >> 1, pw = par & 1;
  int kh = po + 2*(dhw >> 1), kw = pw + 2*(dhw & 1);
  int oc = ocT*16 + (l & 15);
  int ic = icb*32 + (l >> 4)*8 + j;
  f[i] = f2bf(w[(oc*256 + ic)*16 + kh*4 + kw]);
}
// W7F[par4][icb4][dhw4][1 ocT pad16][...], single
__global__ __launch_bounds__(256) void k_w7f(const float* __restrict__ w,
                                             ushort* __restrict__ f){
  int i = blockIdx.x*256 + threadIdx.x;            // 32768
  if (i >= 32768) return;
  int j = i & 7, l = (i >> 3) & 63, rest = i >> 9;
  int dhw = rest & 3, icb = (rest >> 2) & 3, par = (rest >> 4) & 3;
  int po = par >> 1, pw = par & 1;
  int kh = po + 2*(dhw >> 1), kw = pw + 2*(dhw & 1);
  int ocr = l & 15;
  int ic = icb*32 + (l >> 4)*8 + j;
  float v = (ocr < 3) ? w[(ocr*128 + ic)*16 + kh*4 + kw] : 0.f;
  f[i] = f2bf(v);
}
// CBF[codeT32][kst2][...], hi+lo
__global__ __launch_bounds__(256) void k_cbf(const float* __restrict__ cb,
                                             ushort* __restrict__ fh, ushort* __restrict__ fl){
  int i = blockIdx.x*256 + threadIdx.x;            // 32768
  if (i >= 32768) return;
  int j = i & 7, l = (i >> 3) & 63, rest = i >> 9;
  int kst = rest & 1, cT = rest >> 1;
  int code = cT*16 + (l & 15);
  int d = kst*32 + (l >> 4)*8 + j;
  float v = cb[code*64 + d];
  ushort h = f2bf(v);
  fh[i] = h; fl[i] = f2bf(v - bf2f(h));
}
// code norms
__global__ __launch_bounds__(256) void k_cn(const float* __restrict__ cb,
                                            float* __restrict__ cn){
  int c = blockIdx.x*256 + threadIdx.x;
  if (c >= 512) return;
  const float* p = cb + c*64;
  float s = 0.f;
  #pragma unroll
  for (int d = 0; d < 64; d += 4){
    float4 u = *(const float4*)(p + d);
    s = fmaf(u.x,u.x, fmaf(u.y,u.y, fmaf(u.z,u.z, fmaf(u.w,u.w, s))));
  }
  cn[c] = s;
}

// ---- conv1 EXACT fp32 (LDS-staged): x -> H1 hi/lo bf16 NHWC, k4 s2 p1 -----
__global__ __launch_bounds__(256,4) void k_conv1(const float* __restrict__ x,
    const float* __restrict__ w, const float* __restrict__ bias,
    ushort* __restrict__ yh, ushort* __restrict__ yl){
  __shared__ float Xs[12*260];                     // [c*4+kh][260], col = iw+1
  int t = threadIdx.x;
  int bid = blockIdx.x;
  int oh = bid & 127, b = bid >> 7;

  for (int e = t; e < 12*258; e += 256){
    int rowid = e / 258, col = e - rowid*258;
    int c = rowid >> 2, kh = rowid & 3;
    int ih = oh*2 - 1 + kh;
    int iw = col - 1;
    float v = 0.f;
    if ((unsigned)ih < 256u && (unsigned)iw < 256u)
      v = x[(b*3 + c)*65536 + ih*256 + iw];
    Xs[rowid*260 + col] = v;
  }

  int oc = t & 127, half = t >> 7;
  float wv[48];
  const float* wp = w + oc*48;
  #pragma unroll
  for (int i = 0; i < 48; i += 4){
    float4 u = *(const float4*)(wp + i);
    wv[i] = u.x; wv[i+1] = u.y; wv[i+2] = u.z; wv[i+3] = u.w;
  }
  float bv = bias[oc];
  __syncthreads();

  for (int ch = 0; ch < 8; ch++){
    int ow0 = half*64 + ch*8;
    float acc[8];
    #pragma unroll
    for (int i = 0; i < 8; i++) acc[i] = bv;
    #pragma unroll
    for (int c = 0; c < 3; c++){
      #pragma unroll
      for (int kh = 0; kh < 4; kh++){
        const float* lp = Xs + (c*4 + kh)*260 + ow0*2;
        float xr[20];
        #pragma unroll
        for (int q = 0; q < 5; q++){
          float4 u = *(const float4*)(lp + q*4);
          xr[q*4] = u.x; xr[q*4+1] = u.y; xr[q*4+2] = u.z; xr[q*4+3] = u.w;
        }
        #pragma unroll
        for (int i = 0; i < 8; i++){
          #pragma unroll
          for (int kw = 0; kw < 4; kw++)
            acc[i] = fmaf(xr[2*i + kw], wv[c*16 + kh*4 + kw], acc[i]);
        }
      }
    }
    #pragma unroll
    for (int i = 0; i < 8; i++){
      float v = frelu(acc[i]);
      ushort h = f2bf(v);
      ushort l = f2bf(v - bf2f(h));
      int off = ((b*128 + oh)*128 + (ow0 + i))*128 + oc;
      yh[off] = h; yl[off] = l;
    }
  }
}

// ---- conv2: H1 hi/lo -> H2 hi/lo, k4 s2 p1, relu, split-3 MFMA ------------
// tile 8x8 out, all 256 oc; wave = 64 oc x 64 pos. Grid 1024. Halo 18x18.
// LDS parity-deinterleaved [8 par*gq][18 r][9 c2] granules x 2 planes = 41.5KB.
__global__ __launch_bounds__(256,3) void k_conv2(const ushort* __restrict__ xh,
    const ushort* __restrict__ xl,
    const ushort* __restrict__ wfh, const ushort* __restrict__ wfl,
    const float* __restrict__ bias,
    ushort* __restrict__ yh, ushort* __restrict__ yl){
  __shared__ ushort Xs[2*1296*8];                  // 41472B
  int t = threadIdx.x;
  int li = t & 15, g4 = (t >> 4) & 3, lane = t & 63, wq = t >> 6;
  int bid = blockIdx.x;
  int tile = bid & 63, b = bid >> 6;
  int OH0 = (tile >> 3)*8, OW0 = (tile & 7)*8;
  int ih0 = OH0*2 - 1, iw0 = OW0*2 - 1;
  f32x4 acc[4][4];
  #pragma unroll
  for (int m = 0; m < 4; m++)
    #pragma unroll
    for (int n = 0; n < 4; n++) acc[m][n] = (f32x4){0.f,0.f,0.f,0.f};

  int rb = (li >> 3)*2, c8 = li & 7;

  for (int icb = 0; icb < 4; icb++){
    __syncthreads();
    for (int e = t; e < 1296; e += 256){
      int gq = e / 324, cell = e - gq*324;
      int r = cell / 18, c = cell - r*18;
      int ih = ih0 + r, iw = iw0 + c;
      bf16x8 vh = {0,0,0,0,0,0,0,0}, vl = {0,0,0,0,0,0,0,0};
      if ((unsigned)ih < 128u && (unsigned)iw < 128u){
        int off = ((b*128 + ih)*128 + iw)*128 + icb*32 + gq*8;
        vh = *(const bf16x8*)(xh + off);
        vl = *(const bf16x8*)(xl + off);
      }
      int g2 = ((c & 1)*4 + gq)*162 + r*9 + (c >> 1);
      *(bf16x8*)(Xs + g2*8) = vh;
      *(bf16x8*)(Xs + (1296 + g2)*8) = vl;
    }
    __syncthreads();
    for (int khw = 0; khw < 16; khw++){
      int kh = khw >> 2, kw = khw & 3;
      const ushort* aph = wfh + ((khw*4 + icb)*16)*512 + lane*8;
      const ushort* apl = wfl + ((khw*4 + icb)*16)*512 + lane*8;
      bf16x8 Ah[4], Al[4];
      #pragma unroll
      for (int m = 0; m < 4; m++){
        Ah[m] = *(const bf16x8*)(aph + (wq*4 + m)*512);
        Al[m] = *(const bf16x8*)(apl + (wq*4 + m)*512);
      }
      int base0 = (((kw & 1)*4 + g4)*18 + rb + kh)*9 + c8 + (kw >> 1);
      #pragma unroll
      for (int n = 0; n < 4; n++){
        int gran = base0 + n*36;
        bf16x8 Bh = *(const bf16x8*)(Xs + gran*8);
        bf16x8 Bl = *(const bf16x8*)(Xs + (1296 + gran)*8);
        #pragma unroll
        for (int m = 0; m < 4; m++){
          acc[m][n] = MFMA16(Ah[m], Bh, acc[m][n]);
          acc[m][n] = MFMA16(Al[m], Bh, acc[m][n]);
          acc[m][n] = MFMA16(Ah[m], Bl, acc[m][n]);
        }
      }
    }
  }
  #pragma unroll
  for (int m = 0; m < 4; m++){
    f32x4 bv = *(const f32x4*)(bias + wq*64 + m*16 + g4*4);
    #pragma unroll
    for (int n = 0; n < 4; n++){
      int oh = OH0 + 2*n + (li >> 3);
      int ow = OW0 + (li & 7);
      int off = ((b*64 + oh)*64 + ow)*256 + wq*64 + m*16 + g4*4;
      s16x4 h4, l4;
      #pragma unroll
      for (int r = 0; r < 4; r++){
        float v = frelu(acc[m][n][r] + bv[r]);
        ushort h = f2bf(v);
        h4[r] = (short)h;
        l4[r] = (short)f2bf(v - bf2f(h));
      }
      *(s16x4*)(yh + off) = h4;
      *(s16x4*)(yl + off) = l4;
    }
  }
}

// ---- conv3: H2 hi/lo -> ZF f32 [65536][64], k3 s1 p1, split-3 MFMA --------
// tile 8x16, 64 oc; wave = 64 oc x 32 pos (2 n-frags). Grid 512. Halo 10x18.
// LDS 2 planes x 720 granules = 23KB -> 4 blocks/CU.
__global__ __launch_bounds__(256,4) void k_conv3(const ushort* __restrict__ xh,
    const ushort* __restrict__ xl,
    const ushort* __restrict__ wfh, const ushort* __restrict__ wfl,
    const float* __restrict__ bias, float* __restrict__ zf){
  __shared__ ushort Xs[2*720*8];                   // 23040B
  int t = threadIdx.x;
  int li = t & 15, g4 = (t >> 4) & 3, lane = t & 63, wq = t >> 6;
  int bid = blockIdx.x;
  int tile = bid & 31, b = bid >> 5;
  int OH0 = (tile >> 2)*8, OW0 = (tile & 3)*16;
  f32x4 acc[4][2];
  #pragma unroll
  for (int m = 0; m < 4; m++)
    #pragma unroll
    for (int n = 0; n < 2; n++) acc[m][n] = (f32x4){0.f,0.f,0.f,0.f};

  for (int icb = 0; icb < 8; icb++){
    __syncthreads();
    for (int e = t; e < 720; e += 256){
      int gq = e / 180, cell = e - gq*180;
      int r = cell / 18, c = cell - r*18;
      int ih = OH0 - 1 + r, iw = OW0 - 1 + c;
      bf16x8 vh = {0,0,0,0,0,0,0,0}, vl = {0,0,0,0,0,0,0,0};
      if ((unsigned)ih < 64u && (unsigned)iw < 64u){
        int off = ((b*64 + ih)*64 + iw)*256 + icb*32 + gq*8;
        vh = *(const bf16x8*)(xh + off);
        vl = *(const bf16x8*)(xl + off);
      }
      *(bf16x8*)(Xs + e*8) = vh;
      *(bf16x8*)(Xs + (720 + e)*8) = vl;
    }
    __syncthreads();
    #pragma unroll
    for (int kh = 0; kh < 3; kh++){
      #pragma unroll
      for (int kw = 0; kw < 3; kw++){
        int khw = kh*3 + kw;
        const ushort* aph = wfh + ((khw*8 + icb)*4)*512 + lane*8;
        const ushort* apl = wfl + ((khw*8 + icb)*4)*512 + lane*8;
        bf16x8 Ah[4], Al[4];
        #pragma unroll
        for (int m = 0; m < 4; m++){
          Ah[m] = *(const bf16x8*)(aph + m*512);
          Al[m] = *(const bf16x8*)(apl + m*512);
        }
        #pragma unroll
        for (int n = 0; n < 2; n++){
          int gran = g4*180 + (wq*2 + n + kh)*18 + li + kw;
          bf16x8 Bh = *(const bf16x8*)(Xs + gran*8);
          bf16x8 Bl = *(const bf16x8*)(Xs + (720 + gran)*8);
          #pragma unroll
          for (int m = 0; m < 4; m++){
            acc[m][n] = MFMA16(Ah[m], Bh, acc[m][n]);
            acc[m][n] = MFMA16(Al[m], Bh, acc[m][n]);
            acc[m][n] = MFMA16(Ah[m], Bl, acc[m][n]);
          }
        }
      }
    }
  }
  #pragma unroll
  for (int m = 0; m < 4; m++){
    f32x4 bv = *(const f32x4*)(bias + m*16 + g4*4);
    #pragma unroll
    for (int n = 0; n < 2; n++){
      int oh = OH0 + wq*2 + n;
      int ow = OW0 + li;
      int nIdx = (b*64 + oh)*64 + ow;
      f32x4 v = acc[m][n] + bv;
      *(f32x4*)(zf + nIdx*64 + m*16 + g4*4) = v;
    }
  }
}

// ---- vqdist: argmin over 512 codes via split-3 MFMA -----------------------
__global__ __launch_bounds__(256) void k_vqdist(const float* __restrict__ zf,
    const ushort* __restrict__ cfh, const ushort* __restrict__ cfl,
    const float* __restrict__ cn, int* __restrict__ idxOut){
  int t = threadIdx.x;
  int lane = t & 63, wq = t >> 6;
  int li = lane & 15, g = lane >> 4;
  int rowBase = blockIdx.x*64 + wq*16;
  bf16x8 Bh[2], Bl[2];
  const float* zp = zf + (rowBase + li)*64 + g*8;
  #pragma unroll
  for (int kst = 0; kst < 2; kst++){
    float4 u0 = *(const float4*)(zp + kst*32);
    float4 u1 = *(const float4*)(zp + kst*32 + 4);
    float v[8] = {u0.x,u0.y,u0.z,u0.w,u1.x,u1.y,u1.z,u1.w};
    #pragma unroll
    for (int j = 0; j < 8; j++){
      ushort h = f2bf(v[j]);
      Bh[kst][j] = (short)h;
      Bl[kst][j] = (short)f2bf(v[j] - bf2f(h));
    }
  }
  float best = 3.4e38f; int bi = 0;
  for (int ch = 0; ch < 8; ch++){
    f32x4 acc[4];
    #pragma unroll
    for (int m = 0; m < 4; m++) acc[m] = (f32x4){0.f,0.f,0.f,0.f};
    #pragma unroll
    for (int kst = 0; kst < 2; kst++){
      #pragma unroll
      for (int m = 0; m < 4; m++){
        int cT = ch*4 + m;
        bf16x8 Ah = *(const bf16x8*)(cfh + (cT*2 + kst)*512 + lane*8);
        bf16x8 Al = *(const bf16x8*)(cfl + (cT*2 + kst)*512 + lane*8);
        acc[m] = MFMA16(Ah, Bh[kst], acc[m]);
        acc[m] = MFMA16(Al, Bh[kst], acc[m]);
        acc[m] = MFMA16(Ah, Bl[kst], acc[m]);
      }
    }
    #pragma unroll
    for (int m = 0; m < 4; m++){
      #pragma unroll
      for (int r = 0; r < 4; r++){
        int code = (ch*4 + m)*16 + g*4 + r;
        float d2 = cn[code] - 2.f*acc[m][r];
        if (d2 < best){ best = d2; bi = code; }
      }
    }
  }
  #pragma unroll
  for (int off = 32; off >= 16; off >>= 1){
    float ob = __shfl_down(best, off);
    int oi = __shfl_down(bi, off);
    if (ob < best || (ob == best && oi < bi)){ best = ob; bi = oi; }
  }
  if (lane < 16) idxOut[rowBase + li] = bi;
}

// ---- vqgather: q write (bf16) + vq loss -----------------------------------
__global__ __launch_bounds__(256) void k_vqgather(const float* __restrict__ zf,
    const float* __restrict__ cb, const int* __restrict__ idx,
    ushort* __restrict__ qx, float* __restrict__ lossp){
  int n = blockIdx.x*256 + threadIdx.x;
  int code = idx[n];
  const float* cp = cb + code*64;
  const float* zp = zf + n*64;
  float ls = 0.f;
  #pragma unroll
  for (int d = 0; d < 64; d += 4){
    float4 qv = *(const float4*)(cp + d);
    float4 zv = *(const float4*)(zp + d);
    float d0 = qv.x - zv.x, d1 = qv.y - zv.y, d2 = qv.z - zv.z, d3 = qv.w - zv.w;
    ls = fmaf(d0,d0, fmaf(d1,d1, fmaf(d2,d2, fmaf(d3,d3, ls))));
    s16x4 q4;
    q4[0] = (short)f2bf(qv.x); q4[1] = (short)f2bf(qv.y);
    q4[2] = (short)f2bf(qv.z); q4[3] = (short)f2bf(qv.w);
    *(s16x4*)(qx + n*64 + d) = q4;
  }
  #pragma unroll
  for (int off = 32; off > 0; off >>= 1) ls += __shfl_down(ls, off);
  if ((threadIdx.x & 63) == 0) atomicAdd(lossp, ls * (1.25f/4194304.f));
}

// ---- dec1: QX -> D1, k3 s1 p1, relu, single MFMA --------------------------
// tile 16x8, 256 oc; wave = 128 oc x 64 pos.  R=18 C=10.
__global__ __launch_bounds__(256,2) void k_dec1(const ushort* __restrict__ xq,
    const ushort* __restrict__ wf, const float* __restrict__ bias,
    ushort* __restrict__ y){
  __shared__ ushort Xs[720*8];                     // 11520B
  int t = threadIdx.x;
  int li = t & 15, g4 = (t >> 4) & 3, lane = t & 63, wq = t >> 6;
  int och = wq >> 1, ph = wq & 1;
  int bid = blockIdx.x;
  int tile = bid & 31, b = bid >> 5;
  int OH0 = (tile >> 3)*16, OW0 = (tile & 7)*8;
  f32x4 acc[8][4];
  #pragma unroll
  for (int m = 0; m < 8; m++)
    #pragma unroll
    for (int n = 0; n < 4; n++) acc[m][n] = (f32x4){0.f,0.f,0.f,0.f};

  for (int icb = 0; icb < 2; icb++){
    __syncthreads();
    for (int e = t; e < 720; e += 256){
      int gq = e / 180, cell = e - gq*180;
      int r = cell / 10, c = cell - r*10;
      int ih = OH0 - 1 + r, iw = OW0 - 1 + c;
      bf16x8 v = {0,0,0,0,0,0,0,0};
      if ((unsigned)ih < 64u && (unsigned)iw < 64u)
        v = *(const bf16x8*)(xq + ((b*64 + ih)*64 + iw)*64 + icb*32 + gq*8);
      *(bf16x8*)(Xs + e*8) = v;
    }
    __syncthreads();
    #pragma unroll
    for (int kh = 0; kh < 3; kh++){
      #pragma unroll
      for (int kw = 0; kw < 3; kw++){
        int khw = kh*3 + kw;
        const ushort* ap = wf + ((khw*2 + icb)*16)*512 + lane*8;
        bf16x8 A[8];
        #pragma unroll
        for (int m = 0; m < 8; m++)
          A[m] = *(const bf16x8*)(ap + (och*8 + m)*512);
        #pragma unroll
        for (int nn = 0; nn < 4; nn++){
          int nT = ph*4 + nn;
          int gran = g4*180 + (nT*2 + (li >> 3) + kh)*10 + (li & 7) + kw;
          bf16x8 B = *(const bf16x8*)(Xs + gran*8);
          #pragma unroll
          for (int m = 0; m < 8; m++)
            acc[m][nn] = MFMA16(A[m], B, acc[m][nn]);
        }
      }
    }
  }
  #pragma unroll
  for (int m = 0; m < 8; m++){
    int oc = och*128 + m*16 + g4*4;
    f32x4 bv = *(const f32x4*)(bias + oc);
    #pragma unroll
    for (int nn = 0; nn < 4; nn++){
      int nT = ph*4 + nn;
      int oh = OH0 + nT*2 + (li >> 3);
      int ow = OW0 + (li & 7);
      s16x4 h4;
      #pragma unroll
      for (int r = 0; r < 4; r++)
        h4[r] = (short)f2bf(frelu(acc[m][nn][r] + bv[r]));
      *(s16x4*)(y + ((b*64 + oh)*64 + ow)*256 + oc) = h4;
    }
  }
}

// ---- deconv2: D1 -> D2, transposed k4 s2 p1, relu, single MFMA ------------
// out tile 16x16; wave = parity class, 128 oc x 64 pos.  R=10 C=10.
__global__ __launch_bounds__(256,2) void k_deconv2(const ushort* __restrict__ xq,
    const ushort* __restrict__ wf, const float* __restrict__ bias,
    ushort* __restrict__ y){
  __shared__ ushort Xs[400*8];                     // 6400B
  int t = threadIdx.x;
  int li = t & 15, g4 = (t >> 4) & 3, lane = t & 63, wq = t >> 6;
  int po = wq >> 1, pw = wq & 1;
  int bid = blockIdx.x;
  int tile = bid & 63, b = bid >> 6;
  int Y0 = (tile >> 3)*8, X0 = (tile & 7)*8;
  f32x4 acc[8][4];
  #pragma unroll
  for (int m = 0; m < 8; m++)
    #pragma unroll
    for (int n = 0; n < 4; n++) acc[m][n] = (f32x4){0.f,0.f,0.f,0.f};

  for (int icb = 0; icb < 8; icb++){
    __syncthreads();
    for (int e = t; e < 400; e += 256){
      int gq = e / 100, cell = e - gq*100;
      int r = cell / 10, c = cell - r*10;
      int ih = Y0 - 1 + r, iw = X0 - 1 + c;
      bf16x8 v = {0,0,0,0,0,0,0,0};
      if ((unsigned)ih < 64u && (unsigned)iw < 64u)
        v = *(const bf16x8*)(xq + ((b*64 + ih)*64 + iw)*256 + icb*32 + gq*8);
      *(bf16x8*)(Xs + e*8) = v;
    }
    __syncthreads();
    #pragma unroll
    for (int dhw = 0; dhw < 4; dhw++){
      int dh = dhw >> 1, dw = dhw & 1;
      const ushort* ap = wf + (((wq*4 + dhw)*8 + icb)*8)*512 + lane*8;
      bf16x8 A[8];
      #pragma unroll
      for (int m = 0; m < 8; m++)
        A[m] = *(const bf16x8*)(ap + m*512);
      #pragma unroll
      for (int nn = 0; nn < 4; nn++){
        int yy = nn*2 + (li >> 3), xx = li & 7;
        int gran = g4*100 + (yy + dh + po)*10 + xx + dw + pw;
        bf16x8 B = *(const bf16x8*)(Xs + gran*8);
        #pragma unroll
        for (int m = 0; m < 8; m++)
          acc[m][nn] = MFMA16(A[m], B, acc[m][nn]);
      }
    }
  }
  #pragma unroll
  for (int m = 0; m < 8; m++){
    int oc = m*16 + g4*4;
    f32x4 bv = *(const f32x4*)(bias + oc);
    #pragma unroll
    for (int nn = 0; nn < 4; nn++){
      int yy = nn*2 + (li >> 3), xx = li & 7;
      int oh = 2*(Y0 + yy) + po, ow = 2*(X0 + xx) + pw;
      s16x4 h4;
      #pragma unroll
      for (int r = 0; r < 4; r++)
        h4[r] = (short)f2bf(frelu(acc[m][nn][r] + bv[r]));
      *(s16x4*)(y + ((b*128 + oh)*128 + ow)*128 + oc) = h4;
    }
  }
}

// ---- deconv3: D2 -> out f32 NCHW, transposed k4 s2 p1, single MFMA (M pad 16)
// out tile 32x32; wave = parity class, 3 oc x 256 pos.  R=18 C=18.
__global__ __launch_bounds__(256,2) void k_deconv3(const ushort* __restrict__ xq,
    const ushort* __restrict__ wf, const float* __restrict__ bias,
    float* __restrict__ out){
  __shared__ ushort Xs[1296*8];                    // 20736B
  int t = threadIdx.x;
  int li = t & 15, g4 = (t >> 4) & 3, lane = t & 63, wq = t >> 6;
  int po = wq >> 1, pw = wq & 1;
  int bid = blockIdx.x;
  int tile = bid & 63, b = bid >> 6;
  int Y0 = (tile >> 3)*16, X0 = (tile & 7)*16;
  f32x4 acc[16];
  #pragma unroll
  for (int n = 0; n < 16; n++) acc[n] = (f32x4){0.f,0.f,0.f,0.f};

  for (int icb = 0; icb < 4; icb++){
    __syncthreads();
    for (int e = t; e < 1296; e += 256){
      int gq = e / 324, cell = e - gq*324;
      int r = cell / 18, c = cell - r*18;
      int ih = Y0 - 1 + r, iw = X0 - 1 + c;
      bf16x8 v = {0,0,0,0,0,0,0,0};
      if ((unsigned)ih < 128u && (unsigned)iw < 128u)
        v = *(const bf16x8*)(xq + ((b*128 + ih)*128 + iw)*128 + icb*32 + gq*8);
      *(bf16x8*)(Xs + e*8) = v;
    }
    __syncthreads();
    #pragma unroll
    for (int dhw = 0; dhw < 4; dhw++){
      int dh = dhw >> 1, dw = dhw & 1;
      bf16x8 A = *(const bf16x8*)(wf + ((wq*4 + icb)*4 + dhw)*512 + lane*8);
      #pragma unroll
      for (int n = 0; n < 16; n++){
        int gran = g4*324 + (n + dh + po)*18 + li + dw + pw;
        bf16x8 B = *(const bf16x8*)(Xs + gran*8);
        acc[n] = MFMA16(A, B, acc[n]);
      }
    }
  }
  if (g4 == 0){
    float b0 = bias[0], b1 = bias[1], b2 = bias[2];
    #pragma unroll
    for (int n = 0; n < 16; n++){
      int oh = 2*(Y0 + n) + po, ow = 2*(X0 + li) + pw;
      int base = b*196608 + oh*256 + ow;
      out[base]           = acc[n][0] + b0;
      out[base + 65536]   = acc[n][1] + b1;
      out[base + 131072]  = acc[n][2] + b2;
    }
  }
}

// ---------------------------------------------------------------------------
extern "C" void kernel_launch(void* const* d_in, const int* in_sizes, int n_in,
                              void* d_out, int out_size, void* d_ws, size_t ws_size,
                              hipStream_t stream){
  (void)in_sizes; (void)n_in; (void)out_size; (void)ws_size;
  const float* x   = (const float*)d_in[0];
  const float* ew1 = (const float*)d_in[1];
  const float* eb1 = (const float*)d_in[2];
  const float* ew2 = (const float*)d_in[3];
  const float* eb2 = (const float*)d_in[4];
  const float* ew3 = (const float*)d_in[5];
  const float* eb3 = (const float*)d_in[6];
  const float* cb  = (const float*)d_in[7];
  const float* dw1 = (const float*)d_in[8];
  const float* db1 = (const float*)d_in[9];
  const float* dw2 = (const float*)d_in[10];
  const float* db2 = (const float*)d_in[11];
  const float* dw3 = (const float*)d_in[12];
  const float* db3 = (const float*)d_in[13];
  float* out = (float*)d_out;
  char* w = (char*)d_ws;

  ushort* H1H  = (ushort*)(w + 0);
  ushort* H1L  = (ushort*)(w + 67108864);
  ushort* D1   = (ushort*)(w + 0);           // reuse (after conv2)
  ushort* H2H  = (ushort*)(w + 134217728);
  ushort* H2L  = (ushort*)(w + 167772160);
  ushort* QX   = (ushort*)(w + 134217728);   // reuse (after conv3)
  ushort* D2   = (ushort*)(w + 150994944);
  float*  ZF   = (float*)(w + 201326592);
  int*    IDX  = (int*)(w + 218103808);
  ushort* W2FH = (ushort*)(w + 218365952);
  ushort* W2FL = (ushort*)(w + 219414528);
  ushort* W3FH = (ushort*)(w + 220463104);
  ushort* W3FL = (ushort*)(w + 220758016);
  ushort* W5F  = (ushort*)(w + 221052928);
  ushort* W6F  = (ushort*)(w + 221347840);
  ushort* W7F  = (ushort*)(w + 222396416);
  ushort* CBFH = (ushort*)(w + 222461952);
  ushort* CBFL = (ushort*)(w + 222527488);
  float*  CN   = (float*)(w + 222593024);

  k_w2f<<<2048, 256, 0, stream>>>(ew2, W2FH, W2FL);
  k_w3f<<<576,  256, 0, stream>>>(ew3, W3FH, W3FL);
  k_w5f<<<576,  256, 0, stream>>>(dw1, W5F);
  k_w6f<<<2048, 256, 0, stream>>>(dw2, W6F);
  k_w7f<<<128,  256, 0, stream>>>(dw3, W7F);
  k_cbf<<<128,  256, 0, stream>>>(cb, CBFH, CBFL);
  k_cn<<<2,     256, 0, stream>>>(cb, CN);
  k_zero1<<<1, 1, 0, stream>>>(out + 3145728);

  k_conv1<<<2048, 256, 0, stream>>>(x, ew1, eb1, H1H, H1L);
  k_conv2<<<1024, 256, 0, stream>>>(H1H, H1L, W2FH, W2FL, eb2, H2H, H2L);
  k_conv3<<<512,  256, 0, stream>>>(H2H, H2L, W3FH, W3FL, eb3, ZF);
  k_vqdist<<<1024, 256, 0, stream>>>(ZF, CBFH, CBFL, CN, IDX);
  k_vqgather<<<256, 256, 0, stream>>>(ZF, cb, IDX, QX, out + 3145728);
  k_dec1<<<512,   256, 0, stream>>>(QX, W5F, db1, D1);
  k_deconv2<<<1024, 256, 0, stream>>>(D1, W6F, db2, D2);
  k_deconv3<<<1024, 256, 0, stream>>>(D2, W7F, db3, out);
}